// Round 17
// baseline (149.879 us; speedup 1.0000x reference)
//
#include <hip/hip_runtime.h>
#include <hip/hip_bf16.h>
#include <hip/hip_fp16.h>

// Problem constants
#define BATCH 2
#define NPTS  2048
#define CDIM  256
#define NHEAD 8
#define DHEAD 64
#define INNER 512            // NHEAD*DHEAD
#define TRIPLE 1536          // 3*INNER
#define KNN   32
#define NCAND 48             // approximate-select candidate count (margin ~12x)
#define SCALE 0.125f         // 64^-0.5

#define GRAM_ITEMS 272       // 2 batches x 136 upper-tri 128x128 tiles
#define QKV_ITEMS  384       // 32 row-tiles x 12 col-tiles
#define TOTAL_ITEMS (GRAM_ITEMS + QKV_ITEMS)   // 656

#define PREP_BLOCKS 1024     // 4096 rows / 4 rows-per-block
#define WT_BLOCKS   128

typedef __attribute__((ext_vector_type(8))) short short8;      // 8 bf16 (4 VGPR)
typedef __attribute__((ext_vector_type(4))) float floatx4;     // MFMA acc
typedef __attribute__((ext_vector_type(4))) unsigned short ushort4v;
typedef unsigned short ushort;

#define TW  32               // LDS tile row width in ushort (64 B, linear)
#define TSZ (128*TW)         // ushorts per 128-row tile (8192 B)

// bf16 split: x = hi + lo (both RNE bf16). hi in [15:0], lo in [31:16].
__device__ __forceinline__ unsigned bfsplit(float x) {
    unsigned u = __float_as_uint(x);
    unsigned r = u + 0x7fffu + ((u >> 16) & 1u);
    unsigned hs = r >> 16;
    float hf = __uint_as_float(hs << 16);
    float lo = x - hf;
    unsigned u2 = __float_as_uint(lo);
    unsigned r2 = u2 + 0x7fffu + ((u2 >> 16) & 1u);
    return (hs & 0xffffu) | (r2 & 0xffff0000u);
}

// fp16 bit helpers
__device__ __forceinline__ ushort f2h(float f) {
    __half h = __float2half(f);               // RNE
    return *reinterpret_cast<ushort*>(&h);
}
__device__ __forceinline__ float h2f(ushort u) {
    __half h;
    *reinterpret_cast<ushort*>(&h) = u;
    return __half2float(h);
}

// ---------------------------------------------------------------------------
// Kernel 1 (merged prep): blocks 0..1023 = rowsq + x hi/lo split;
// blocks 1024..1151 = weight transpose+split (both matrices).
// ---------------------------------------------------------------------------
__global__ __launch_bounds__(256) void prep_kernel(const float* __restrict__ x,
                                                   float* __restrict__ x2,
                                                   ushort* __restrict__ xhi,
                                                   ushort* __restrict__ xlo,
                                                   const float* __restrict__ Wqkv,
                                                   const float* __restrict__ Wout,
                                                   ushort* __restrict__ wqhiT,
                                                   ushort* __restrict__ wqloT,
                                                   ushort* __restrict__ wohiT,
                                                   ushort* __restrict__ woloT) {
    __shared__ float tile[64][65];
    int gbid = blockIdx.x;
    if (gbid < PREP_BLOCKS) {
        int wave = threadIdx.x >> 6, lane = threadIdx.x & 63;
        int row = gbid * 4 + wave;
        const float* xr = x + (size_t)row * CDIM;
        float4 v = *(const float4*)(xr + lane * 4);
        float s = v.x*v.x + v.y*v.y + v.z*v.z + v.w*v.w;
        #pragma unroll
        for (int o = 32; o; o >>= 1) s += __shfl_down(s, o);
        if (lane == 0) x2[row] = s;

        unsigned p0 = bfsplit(v.x), p1 = bfsplit(v.y),
                 p2 = bfsplit(v.z), p3 = bfsplit(v.w);
        ushort4v h, l;
        h.x = (ushort)p0; l.x = (ushort)(p0 >> 16);
        h.y = (ushort)p1; l.y = (ushort)(p1 >> 16);
        h.z = (ushort)p2; l.z = (ushort)(p2 >> 16);
        h.w = (ushort)p3; l.w = (ushort)(p3 >> 16);
        size_t off = (size_t)row * CDIM + lane * 4;
        *(ushort4v*)(xhi + off) = h;
        *(ushort4v*)(xlo + off) = l;
        return;
    }

    int bid = gbid - PREP_BLOCKS;
    const float* W; ushort* hiT; ushort* loT; int K, N, bx, by;
    if (bid < 96) { W = Wqkv; hiT = wqhiT; loT = wqloT; K = CDIM;  N = TRIPLE; bx = bid % 24; by = bid / 24; }
    else { int t = bid - 96; W = Wout; hiT = wohiT; loT = woloT; K = INNER; N = CDIM;  bx = t % 4;  by = t / 4; }
    int k0 = by * 64, n0 = bx * 64;
    #pragma unroll
    for (int i = 0; i < 4; ++i) {
        int f = threadIdx.x + i * 256;
        int r = f >> 4, c4 = (f & 15) * 4;
        float4 v = *(const float4*)(W + (size_t)(k0 + r) * N + n0 + c4);
        tile[r][c4+0] = v.x; tile[r][c4+1] = v.y;
        tile[r][c4+2] = v.z; tile[r][c4+3] = v.w;
    }
    __syncthreads();
    #pragma unroll
    for (int i = 0; i < 4; ++i) {
        int f = threadIdx.x + i * 256;
        int rn = f >> 4, ck = (f & 15) * 4;
        unsigned p0 = bfsplit(tile[ck+0][rn]);
        unsigned p1 = bfsplit(tile[ck+1][rn]);
        unsigned p2 = bfsplit(tile[ck+2][rn]);
        unsigned p3 = bfsplit(tile[ck+3][rn]);
        ushort4v h, l;
        h.x = (ushort)p0; l.x = (ushort)(p0 >> 16);
        h.y = (ushort)p1; l.y = (ushort)(p1 >> 16);
        h.z = (ushort)p2; l.z = (ushort)(p2 >> 16);
        h.w = (ushort)p3; l.w = (ushort)(p3 >> 16);
        *(ushort4v*)(hiT + (size_t)(n0 + rn) * K + k0 + ck) = h;
        *(ushort4v*)(loT + (size_t)(n0 + rn) * K + k0 + ck) = l;
    }
}

// ---------------------------------------------------------------------------
// MFMA bodies: register-staged global->LDS + linear TW=32 tiles with
// chunk-XOR swizzle -> conflict-free reads, compiler hoists prefetch.
// ---------------------------------------------------------------------------

// GEMM body (hi/lo, 3 products hh+hl+lh). Two output modes:
//  - qkv mode (kv16 != nullptr): cols <512 -> q fp32 [row][512];
//    cols >=512 -> kv16 fp16 [row][1024]. C holds q.
//  - plain mode: C[row*N+col] = acc + bias.
__device__ __forceinline__ void gemm_split_body(const ushort* __restrict__ Ahi,
                                                const ushort* __restrict__ Alo,
                                                const ushort* __restrict__ BhiT,
                                                const ushort* __restrict__ BloT,
                                                const float* __restrict__ bias,
                                                float* __restrict__ C,
                                                int N, int K, int bi, int bj,
                                                ushort* lds,
                                                ushort* __restrict__ kv16) {
    int lane = threadIdx.x & 63, wave = threadIdx.x >> 6;
    int wr = wave >> 1, wc = wave & 1;
    int fr = lane & 15, kg = lane >> 4;
    int swz8 = (kg ^ ((fr >> 1) & 3)) * 8;      // read-side chunk swizzle

    int srow = threadIdx.x >> 1;                // 0..127
    int hc = (threadIdx.x & 1) * 2;             // global chunk base: 0 or 2
    int sw = (srow >> 1) & 3;                   // row swizzle key
    int d0 = srow * TW + ((hc + 0) ^ sw) * 8;   // LDS dests (swizzled)
    int d1 = srow * TW + ((hc + 1) ^ sw) * 8;

    const ushort* g0 = Ahi  + (size_t)(bi + srow) * K + hc * 8;
    const ushort* g1 = Alo  + (size_t)(bi + srow) * K + hc * 8;
    const ushort* g2 = BhiT + (size_t)(bj + srow) * K + hc * 8;
    const ushort* g3 = BloT + (size_t)(bj + srow) * K + hc * 8;

    floatx4 acc[4][4] = {};

    for (int k0 = 0; k0 < K; k0 += 32) {
        uint4 va0 = *(const uint4*)(g0 + k0);
        uint4 va1 = *(const uint4*)(g0 + k0 + 8);
        uint4 vb0 = *(const uint4*)(g1 + k0);
        uint4 vb1 = *(const uint4*)(g1 + k0 + 8);
        uint4 vc0 = *(const uint4*)(g2 + k0);
        uint4 vc1 = *(const uint4*)(g2 + k0 + 8);
        uint4 vd0 = *(const uint4*)(g3 + k0);
        uint4 vd1 = *(const uint4*)(g3 + k0 + 8);
        *(uint4*)&lds[0*TSZ + d0] = va0;  *(uint4*)&lds[0*TSZ + d1] = va1;
        *(uint4*)&lds[1*TSZ + d0] = vb0;  *(uint4*)&lds[1*TSZ + d1] = vb1;
        *(uint4*)&lds[2*TSZ + d0] = vc0;  *(uint4*)&lds[2*TSZ + d1] = vc1;
        *(uint4*)&lds[3*TSZ + d0] = vd0;  *(uint4*)&lds[3*TSZ + d1] = vd1;
        __syncthreads();

        short8 a_h[4], a_l[4], b_h[4], b_l[4];
        #pragma unroll
        for (int m = 0; m < 4; ++m) {
            int off = (wr*64 + m*16 + fr) * TW + swz8;
            a_h[m] = *(const short8*)&lds[0*TSZ + off];
            a_l[m] = *(const short8*)&lds[1*TSZ + off];
        }
        #pragma unroll
        for (int n = 0; n < 4; ++n) {
            int off = (wc*64 + n*16 + fr) * TW + swz8;
            b_h[n] = *(const short8*)&lds[2*TSZ + off];
            b_l[n] = *(const short8*)&lds[3*TSZ + off];
        }
        #pragma unroll
        for (int m = 0; m < 4; ++m)
            #pragma unroll
            for (int n = 0; n < 4; ++n) {
                acc[m][n] = __builtin_amdgcn_mfma_f32_16x16x32_bf16(a_h[m], b_h[n], acc[m][n], 0, 0, 0);
                acc[m][n] = __builtin_amdgcn_mfma_f32_16x16x32_bf16(a_h[m], b_l[n], acc[m][n], 0, 0, 0);
                acc[m][n] = __builtin_amdgcn_mfma_f32_16x16x32_bf16(a_l[m], b_h[n], acc[m][n], 0, 0, 0);
            }
        __syncthreads();
    }

    if (kv16) {
        // qkv mode: q fp32 compact + k/v fp16 only (block cols are uniform)
        bool is_q = (bj < INNER);
        #pragma unroll
        for (int m = 0; m < 4; ++m)
            #pragma unroll
            for (int n = 0; n < 4; ++n) {
                int col = bj + wc*64 + n*16 + fr;
                #pragma unroll
                for (int r = 0; r < 4; ++r) {
                    int row = bi + wr*64 + m*16 + kg*4 + r;
                    float val = acc[m][n][r];
                    if (is_q) C[(size_t)row * INNER + col] = val;
                    else      kv16[(size_t)row * 1024 + (col - INNER)] = f2h(val);
                }
            }
    } else {
        #pragma unroll
        for (int m = 0; m < 4; ++m)
            #pragma unroll
            for (int n = 0; n < 4; ++n) {
                int col = bj + wc*64 + n*16 + fr;
                float bv = bias ? bias[col] : 0.0f;
                #pragma unroll
                for (int r = 0; r < 4; ++r) {
                    int row = bi + wr*64 + m*16 + kg*4 + r;
                    C[(size_t)row * N + col] = acc[m][n][r] + bv;
                }
            }
    }
}

// Gram body (APPROXIMATE): single hh product -> S~ used only to pick
// top-NCAND candidates per row (true top-32 inside with ~12x margin;
// exact fp32 rescoring happens in knn_attn). Mirror write as before.
__device__ __forceinline__ void gram_approx_body(const ushort* __restrict__ Ah,
                                                 const float* __restrict__ x2b,
                                                 float* __restrict__ Sb,
                                                 int bi, int bj, ushort* lds) {
    int lane = threadIdx.x & 63, wave = threadIdx.x >> 6;
    int wr = wave >> 1, wc = wave & 1;
    int fr = lane & 15, kg = lane >> 4;
    int swz8 = (kg ^ ((fr >> 1) & 3)) * 8;

    int srow = threadIdx.x >> 1;
    int hc = (threadIdx.x & 1) * 2;
    int sw = (srow >> 1) & 3;
    int d0 = srow * TW + ((hc + 0) ^ sw) * 8;
    int d1 = srow * TW + ((hc + 1) ^ sw) * 8;

    const ushort* g0 = Ah + (size_t)(bi + srow) * CDIM + hc * 8;
    const ushort* g1 = Ah + (size_t)(bj + srow) * CDIM + hc * 8;

    floatx4 acc[4][4] = {};

    for (int k0 = 0; k0 < CDIM; k0 += 32) {
        uint4 a0 = *(const uint4*)(g0 + k0); uint4 a1 = *(const uint4*)(g0 + k0 + 8);
        uint4 e0 = *(const uint4*)(g1 + k0); uint4 e1 = *(const uint4*)(g1 + k0 + 8);
        *(uint4*)&lds[0*TSZ + d0] = a0; *(uint4*)&lds[0*TSZ + d1] = a1;
        *(uint4*)&lds[1*TSZ + d0] = e0; *(uint4*)&lds[1*TSZ + d1] = e1;
        __syncthreads();

        short8 a_h[4], b_h[4];
        #pragma unroll
        for (int m = 0; m < 4; ++m) {
            int off = (wr*64 + m*16 + fr) * TW + swz8;
            a_h[m] = *(const short8*)&lds[0*TSZ + off];
        }
        #pragma unroll
        for (int n = 0; n < 4; ++n) {
            int off = (wc*64 + n*16 + fr) * TW + swz8;
            b_h[n] = *(const short8*)&lds[1*TSZ + off];
        }
        #pragma unroll
        for (int m = 0; m < 4; ++m)
            #pragma unroll
            for (int n = 0; n < 4; ++n)
                acc[m][n] = __builtin_amdgcn_mfma_f32_16x16x32_bf16(a_h[m], b_h[n], acc[m][n], 0, 0, 0);
        __syncthreads();
    }

    // normal write: S~[bi+row][bj+col] = x2[col] - 2 acc (diag -> inf)
    #pragma unroll
    for (int m = 0; m < 4; ++m)
        #pragma unroll
        for (int n = 0; n < 4; ++n) {
            int col = bj + wc*64 + n*16 + fr;
            float xc = x2b[col];
            #pragma unroll
            for (int r = 0; r < 4; ++r) {
                int row = bi + wr*64 + m*16 + kg*4 + r;
                float val = xc - 2.0f * acc[m][n][r];
                if (row == col) val = __builtin_inff();
                Sb[(size_t)row * NPTS + col] = val;
            }
        }

    // mirror write: S~[bj+col][bi+row] = x2[row] - 2 acc, via LDS transpose
    if (bi != bj) {
        float* T = (float*)lds;                 // 64 x 128, stride 132 floats
        #pragma unroll
        for (int p = 0; p < 2; ++p) {
            __syncthreads();
            if (wc == p) {
                #pragma unroll
                for (int m = 0; m < 4; ++m) {
                    int row0 = wr*64 + m*16 + kg*4;
                    float x0 = x2b[bi + row0 + 0];
                    float x1 = x2b[bi + row0 + 1];
                    float x2v = x2b[bi + row0 + 2];
                    float x3 = x2b[bi + row0 + 3];
                    #pragma unroll
                    for (int n = 0; n < 4; ++n) {
                        int colp = n*16 + fr;   // 0..63 within pass
                        float4 v;
                        v.x = x0 - 2.0f * acc[m][n][0];
                        v.y = x1 - 2.0f * acc[m][n][1];
                        v.z = x2v - 2.0f * acc[m][n][2];
                        v.w = x3 - 2.0f * acc[m][n][3];
                        *(float4*)&T[colp * 132 + row0] = v;
                    }
                }
            }
            __syncthreads();
            #pragma unroll
            for (int i = 0; i < 8; ++i) {
                int f = threadIdx.x + i * 256;  // 0..2047
                int cr = f >> 5, c4 = (f & 31) * 4;
                float4 v = *(const float4*)&T[cr * 132 + c4];
                *(float4*)(Sb + (size_t)(bj + p*64 + cr) * NPTS + bi + c4) = v;
            }
        }
    }
}

// ---------------------------------------------------------------------------
// Kernel 2: static-grid MFMA kernel, sequential item order.
// Items 0..271 gram-approx, 272..655 qkv (q fp32 + k/v fp16 emit).
// LDS = max(Tmir 33792 B, qkv 4 tiles 32768 B) = 33792 B -> 4 blocks/CU.
// ---------------------------------------------------------------------------
__global__ __launch_bounds__(256) void fused_mfma_kernel(const ushort* __restrict__ xh,
                                                         const ushort* __restrict__ xl,
                                                         const float* __restrict__ x2,
                                                         float* __restrict__ S,
                                                         const ushort* __restrict__ wqhiT,
                                                         const ushort* __restrict__ wqloT,
                                                         float* __restrict__ q,
                                                         ushort* __restrict__ kv16) {
    __shared__ ushort lds[16896];    // 33792 B
    int item = blockIdx.x;
    if (item < GRAM_ITEMS) {
        int b = item / 136, t = item % 136;
        int by = 0;
        while (t >= 16 - by) { t -= 16 - by; ++by; }
        int bx = by + t;                 // by <= bx (upper triangle)
        size_t xoff = (size_t)b * NPTS * CDIM;
        gram_approx_body(xh + xoff, x2 + (size_t)b * NPTS,
                         S + (size_t)b * NPTS * NPTS,
                         by * 128, bx * 128, lds);
    } else {
        int t = item - GRAM_ITEMS;       // 0..383
        int bx = t % 12, by = t / 12;
        gemm_split_body(xh, xl, wqhiT, wqloT, nullptr, q,
                        TRIPLE, CDIM, by * 128, bx * 128, lds, kv16);
    }
}

// ---------------------------------------------------------------------------
// Kernel 3: out projection (staged split GEMM + bias).
// ---------------------------------------------------------------------------
__global__ __launch_bounds__(256) void outproj_kernel(const ushort* __restrict__ Ahi,
                                                      const ushort* __restrict__ Alo,
                                                      const ushort* __restrict__ BhiT,
                                                      const ushort* __restrict__ BloT,
                                                      const float* __restrict__ bias,
                                                      float* __restrict__ C) {
    __shared__ ushort lds[4*TSZ];    // 32 KB
    gemm_split_body(Ahi, Alo, BhiT, BloT, bias, C,
                    CDIM, INNER, blockIdx.y * 128, blockIdx.x * 128, lds, nullptr);
}

// ---------------------------------------------------------------------------
// Kernel 4 (fused): approx top-NCAND selection + exact fp32 rescoring ->
// exact top-32 + sparse attention, one block per (b,n).
// ---------------------------------------------------------------------------
__device__ __forceinline__ unsigned block_excl_scan_256(unsigned c,
                                                        unsigned* wsum,
                                                        unsigned* total_out) {
    unsigned v = c;
    #pragma unroll
    for (int o = 1; o < 64; o <<= 1) {
        unsigned t = __shfl_up(v, o);
        if ((threadIdx.x & 63) >= o) v += t;
    }
    if ((threadIdx.x & 63) == 63) wsum[threadIdx.x >> 6] = v;
    __syncthreads();
    unsigned woff = 0;
    int mywave = threadIdx.x >> 6;
    #pragma unroll
    for (int w = 0; w < 4; ++w) {
        unsigned s = wsum[w];
        if (w < mywave) woff += s;
    }
    if (total_out) *total_out = wsum[0] + wsum[1] + wsum[2] + wsum[3];
    __syncthreads();
    return v + woff - c;
}

__global__ __launch_bounds__(256) void knn_attn_kernel(const float* __restrict__ S,
                                                       const float* __restrict__ x,
                                                       const float* __restrict__ x2,
                                                       const float* __restrict__ q,
                                                       const ushort* __restrict__ kv16,
                                                       ushort* __restrict__ ahi,
                                                       ushort* __restrict__ alo) {
    int bid = blockIdx.x;
    int b = (bid & 7) >> 2;
    int n = ((bid >> 3) << 2) | (bid & 3);
    size_t rowoff = (size_t)b * NPTS + n;
    const float* row = S + rowoff * NPTS;
    const float* xb  = x + (size_t)b * NPTS * CDIM;
    const float* x2b = x2 + (size_t)b * NPTS;

    __shared__ unsigned keys[NPTS];
    __shared__ unsigned hist[256];
    __shared__ unsigned wsum[4];
    __shared__ unsigned s_red[8];
    __shared__ unsigned sh_lo, sh_hi, sh_rank, sh_cnt, sh_break;
    __shared__ unsigned ckey[64];
    __shared__ int     cidx[64];
    __shared__ unsigned s_ccount;
    __shared__ int   cand[NCAND];
    __shared__ float dex[NCAND];
    __shared__ int   nb[KNN];
    __shared__ float dots[NHEAD][KNN];
    __shared__ float p[NHEAD][KNN];

    int tid = threadIdx.x;

    // ---- stage 1: approximate top-NCAND via histogram select on S~ ----
    unsigned mn = 0xffffffffu, mx = 0u;
    {
        int i0 = tid * 8;
        float4 f0 = *(const float4*)(row + i0);
        float4 f1 = *(const float4*)(row + i0 + 4);
        float fv[8] = { f0.x, f0.y, f0.z, f0.w, f1.x, f1.y, f1.z, f1.w };
        #pragma unroll
        for (int t = 0; t < 8; ++t) {
            int i = i0 + t;
            unsigned u;
            if (i == n) {
                u = 0xffffffffu;
            } else {
                unsigned v = __float_as_uint(fv[t]);
                u = (v & 0x80000000u) ? ~v : (v | 0x80000000u);
                mn = min(mn, u); mx = max(mx, u);
            }
            keys[i] = u;
        }
    }
    #pragma unroll
    for (int o = 32; o; o >>= 1) {
        mn = min(mn, (unsigned)__shfl_xor((int)mn, o));
        mx = max(mx, (unsigned)__shfl_xor((int)mx, o));
    }
    if ((tid & 63) == 0) { s_red[tid >> 6] = mn; s_red[4 + (tid >> 6)] = mx; }
    __syncthreads();
    if (tid == 0) {
        unsigned a = min(min(s_red[0], s_red[1]), min(s_red[2], s_red[3]));
        unsigned z = max(max(s_red[4], s_red[5]), max(s_red[6], s_red[7]));
        sh_lo = a; sh_hi = z; sh_rank = NCAND; sh_break = 0; s_ccount = 0;
    }
    __syncthreads();

    for (int it = 0; it < 5; ++it) {
        unsigned lo = sh_lo, hi = sh_hi;
        unsigned range1 = hi - lo;
        int shift = 0;
        if (range1 > 255u) shift = 24 - __clz(range1);
        hist[tid] = 0;
        __syncthreads();
        for (int i = tid; i < NPTS; i += 256) {
            unsigned u = keys[i];
            if (u >= lo && u <= hi)
                atomicAdd(&hist[(u - lo) >> shift], 1u);
        }
        __syncthreads();
        unsigned c = hist[tid];
        unsigned rank = sh_rank;
        unsigned excl = block_excl_scan_256(c, wsum, nullptr);
        if (excl < rank && excl + c >= rank) {
            sh_rank = rank - excl;
            unsigned nlo = lo + ((unsigned)tid << shift);
            unsigned span = (shift == 0) ? 0u : (((1u << shift)) - 1u);
            unsigned nhi = nlo + span;
            if (nhi > hi || nhi < nlo) nhi = hi;
            sh_lo = nlo; sh_hi = nhi;
            sh_cnt = c;
            sh_break = (shift == 0 || c <= 64u) ? 1u : 0u;
        }
        __syncthreads();
        if (sh_break) break;
    }

    unsigned lo = sh_lo, hi = sh_hi, rank = sh_rank, cnt = sh_cnt;

    unsigned lt = 0;
    for (int i = tid; i < NPTS; i += 256) lt += (keys[i] < lo) ? 1u : 0u;
    unsigned pos = block_excl_scan_256(lt, wsum, nullptr);
    for (int i = tid; i < NPTS; i += 256) {
        unsigned u = keys[i];
        if (u < lo) cand[pos++] = i;
        else if (u >= lo && u <= hi && cnt <= 64u) {
            unsigned pp = atomicAdd(&s_ccount, 1u);
            ckey[pp] = u; cidx[pp] = i;
        }
    }
    __syncthreads();

    unsigned base = NCAND - rank;
    if (cnt <= 64u) {
        if (tid < (int)cnt) {
            unsigned myk = ckey[tid]; int myi = cidx[tid];
            unsigned r = 0;
            for (unsigned s = 0; s < cnt; ++s) {
                unsigned sk = ckey[s]; int si = cidx[s];
                r += (sk < myk || (sk == myk && si < myi)) ? 1u : 0u;
            }
            if (r < rank) cand[base + r] = myi;
        }
    } else {
        if (tid == 0) {
            unsigned need = rank, pp = base;
            for (int i = 0; i < NPTS && need; ++i) {
                if (keys[i] >= lo && keys[i] <= hi) { cand[pp++] = i; --need; }
            }
        }
    }
    __syncthreads();

    // ---- stage 2: exact fp32 rescoring of the NCAND candidates ----
    {
        int g = tid >> 2;              // candidate 0..63 (48 active)
        int ln = tid & 3;              // 4 lanes per candidate, 64 dims each
        if (g < NCAND) {
            const float* xc = xb + (size_t)cand[g] * CDIM + ln * 64;
            const float* xq = xb + (size_t)n * CDIM + ln * 64;
            float dot = 0.f;
            #pragma unroll
            for (int t = 0; t < 16; ++t) {
                float4 a = *(const float4*)(xc + t * 4);
                float4 bq = *(const float4*)(xq + t * 4);
                dot += a.x*bq.x + a.y*bq.y + a.z*bq.z + a.w*bq.w;
            }
            dot += __shfl_xor(dot, 1);
            dot += __shfl_xor(dot, 2);
            if (ln == 0) dex[g] = x2b[cand[g]] - 2.0f * dot;
        }
    }
    __syncthreads();

    // exact top-32 among candidates (rank-by-count, ties -> lowest index)
    if (tid < NCAND) {
        float myd = dex[tid]; int myi = cand[tid];
        unsigned r = 0;
        for (int s = 0; s < NCAND; ++s) {
            float sd = dex[s]; int si = cand[s];
            r += (sd < myd || (sd == myd && si < myi)) ? 1u : 0u;
        }
        if (r < KNN) nb[r] = myi;
    }
    __syncthreads();

    // ---- attention phase (fp16 K/V gather, fp32 math) ----
    const float* qrow = q + rowoff * INNER;
    const ushort* kvb = kv16 + (size_t)b * NPTS * 1024;

    // phase 1: dots
    {
        int j = tid >> 3;              // neighbor 0..31
        int l = tid & 7;               // 8-elem segment 0..7
        const ushort* krow = kvb + (size_t)nb[j] * 1024 + l * 8;   // k at 0..511
        short8 kr[NHEAD];
        #pragma unroll
        for (int h = 0; h < NHEAD; ++h)
            kr[h] = *(const short8*)(krow + h * DHEAD);
        const float* qp = qrow + l * 8;
        #pragma unroll
        for (int h = 0; h < NHEAD; ++h) {
            float4 q0 = *(const float4*)(qp + h * DHEAD);
            float4 q1 = *(const float4*)(qp + h * DHEAD + 4);
            float d = h2f((ushort)kr[h][0]) * q0.x + h2f((ushort)kr[h][1]) * q0.y
                    + h2f((ushort)kr[h][2]) * q0.z + h2f((ushort)kr[h][3]) * q0.w
                    + h2f((ushort)kr[h][4]) * q1.x + h2f((ushort)kr[h][5]) * q1.y
                    + h2f((ushort)kr[h][6]) * q1.z + h2f((ushort)kr[h][7]) * q1.w;
            d += __shfl_xor(d, 1);
            d += __shfl_xor(d, 2);
            d += __shfl_xor(d, 4);
            if (l == 0) dots[h][j] = d * SCALE;
        }
    }
    __syncthreads();

    // phase 1b: softmax per head
    {
        int h = tid >> 5, jj = tid & 31;
        float dv = dots[h][jj];
        float mxv = dv;
        for (int o = 16; o; o >>= 1) mxv = fmaxf(mxv, __shfl_xor(mxv, o));
        float e = expf(dv - mxv);
        float s = e;
        for (int o = 16; o; o >>= 1) s += __shfl_xor(s, o);
        p[h][jj] = e / s;
    }
    __syncthreads();

    // phase 2: weighted V sum (fp16 V), 8 loads in flight per group
    {
        int hd = tid >> 5;
        int jd = tid & 31;
        const ushort* vb = kvb + INNER + hd * DHEAD + jd * 2;      // v at 512..1023
        float o0 = 0.f, o1 = 0.f;
        #pragma unroll
        for (int g = 0; g < 4; ++g) {
            unsigned vv[8]; float pw[8];
            #pragma unroll
            for (int t = 0; t < 8; ++t) {
                int jj = g * 8 + t;
                vv[t] = *(const unsigned*)(vb + (size_t)nb[jj] * 1024);
                pw[t] = p[hd][jj];
            }
            #pragma unroll
            for (int t = 0; t < 8; ++t) {
                o0 += pw[t] * h2f((ushort)(vv[t] & 0xffffu));
                o1 += pw[t] * h2f((ushort)(vv[t] >> 16));
            }
        }
        size_t baseo = rowoff * INNER + hd * DHEAD + jd * 2;
        unsigned q0 = bfsplit(o0);
        unsigned q1 = bfsplit(o1);
        *(unsigned*)(ahi + baseo) = (q0 & 0xffffu) | (q1 << 16);
        *(unsigned*)(alo + baseo) = (q0 >> 16) | (q1 & 0xffff0000u);
    }
}

// ---------------------------------------------------------------------------
extern "C" void kernel_launch(void* const* d_in, const int* in_sizes, int n_in,
                              void* d_out, int out_size, void* d_ws, size_t ws_size,
                              hipStream_t stream) {
    const float* x    = (const float*)d_in[0];   // [2,2048,256]
    const float* Wqkv = (const float*)d_in[1];   // [256,1536]
    const float* Wout = (const float*)d_in[2];   // [512,256]
    const float* bout = (const float*)d_in[3];   // [256]
    float* out = (float*)d_out;                  // [2,2048,256]

    // workspace layout
    float* S     = (float*)d_ws;                           // B*N*N f32
    float* x2    = S + (size_t)BATCH * NPTS * NPTS;        // B*N f32
    float* q     = x2 + (size_t)BATCH * NPTS;              // B*N*512 f32
    ushort* kv16 = (ushort*)(q + (size_t)BATCH * NPTS * INNER); // B*N*1024 fp16
    ushort* xhi  = kv16 + (size_t)BATCH * NPTS * 1024;
    ushort* xlo   = xhi   + (size_t)BATCH * NPTS * CDIM;
    ushort* ahi   = xlo   + (size_t)BATCH * NPTS * CDIM;
    ushort* alo   = ahi   + (size_t)BATCH * NPTS * INNER;
    ushort* wqhiT = alo   + (size_t)BATCH * NPTS * INNER;  // [1536][256]
    ushort* wqloT = wqhiT + (size_t)TRIPLE * CDIM;
    ushort* wohiT = wqloT + (size_t)TRIPLE * CDIM;         // [256][512]
    ushort* woloT = wohiT + (size_t)CDIM * INNER;

    // 1. merged prep: rowsq + x split + weight transposes
    prep_kernel<<<PREP_BLOCKS + WT_BLOCKS, 256, 0, stream>>>(
        x, x2, xhi, xlo, Wqkv, Wout, wqhiT, wqloT, wohiT, woloT);

    // 2. static gram-approx (upper-tri + mirror) + qkv GEMM
    fused_mfma_kernel<<<TOTAL_ITEMS, 256, 0, stream>>>(xhi, xlo, x2, S,
                                                       wqhiT, wqloT, q, kv16);

    // 3. fused approx-select + exact rescoring + sparse attention
    knn_attn_kernel<<<BATCH * NPTS, 256, 0, stream>>>(S, x, x2, q, kv16, ahi, alo);

    // 4. output projection: [4096,512] @ [512,256] + bias
    {
        dim3 grid(CDIM / 128, (BATCH * NPTS) / 128);
        outproj_kernel<<<grid, 256, 0, stream>>>(ahi, alo, wohiT, woloT, bout, out);
    }
}

// Round 18
// 104.294 us; speedup vs baseline: 1.4371x; 1.4371x over previous
//
#include <hip/hip_runtime.h>
#include <hip/hip_bf16.h>
#include <hip/hip_fp16.h>

// Problem constants
#define BATCH 2
#define NPTS  2048
#define CDIM  256
#define NHEAD 8
#define DHEAD 64
#define INNER 512            // NHEAD*DHEAD
#define TRIPLE 1536          // 3*INNER
#define KNN   32
#define SCALE 0.125f         // 64^-0.5

#define GRAM_ITEMS 272       // 2 batches x 136 upper-tri 128x128 tiles
#define QKV_ITEMS  384       // 32 row-tiles x 12 col-tiles
#define TOTAL_ITEMS (GRAM_ITEMS + QKV_ITEMS)   // 656

#define PREP_BLOCKS 1024     // 4096 rows / 4 rows-per-block
#define WT_BLOCKS   128

typedef __attribute__((ext_vector_type(8))) short short8;      // 8 bf16 (4 VGPR)
typedef __attribute__((ext_vector_type(4))) float floatx4;     // MFMA acc
typedef __attribute__((ext_vector_type(4))) unsigned short ushort4v;
typedef unsigned short ushort;

#define TW  32               // LDS tile row width in ushort (64 B, linear)
#define TSZ (128*TW)         // ushorts per 128-row tile (8192 B)

// bf16 split: x = hi + lo (both RNE bf16). hi in [15:0], lo in [31:16].
__device__ __forceinline__ unsigned bfsplit(float x) {
    unsigned u = __float_as_uint(x);
    unsigned r = u + 0x7fffu + ((u >> 16) & 1u);
    unsigned hs = r >> 16;
    float hf = __uint_as_float(hs << 16);
    float lo = x - hf;
    unsigned u2 = __float_as_uint(lo);
    unsigned r2 = u2 + 0x7fffu + ((u2 >> 16) & 1u);
    return (hs & 0xffffu) | (r2 & 0xffff0000u);
}

// 3-component split: x = h + l + q, residual ~2^-27 relative.
__device__ __forceinline__ void bfsplit3(float x, ushort* hh, ushort* ll, ushort* qq) {
    unsigned u = __float_as_uint(x);
    unsigned r = u + 0x7fffu + ((u >> 16) & 1u);
    unsigned hs = r >> 16;
    float hf = __uint_as_float(hs << 16);
    float d1 = x - hf;
    unsigned u2 = __float_as_uint(d1);
    unsigned r2 = u2 + 0x7fffu + ((u2 >> 16) & 1u);
    unsigned ls = r2 >> 16;
    float lf = __uint_as_float(ls << 16);
    float d2 = d1 - lf;
    unsigned u3 = __float_as_uint(d2);
    unsigned r3 = u3 + 0x7fffu + ((u3 >> 16) & 1u);
    *hh = (ushort)hs;
    *ll = (ushort)ls;
    *qq = (ushort)(r3 >> 16);
}

// fp16 bit helpers
__device__ __forceinline__ ushort f2h(float f) {
    __half h = __float2half(f);               // RNE
    return *reinterpret_cast<ushort*>(&h);
}
__device__ __forceinline__ float h2f(ushort u) {
    __half h;
    *reinterpret_cast<ushort*>(&h) = u;
    return __half2float(h);
}

// ---------------------------------------------------------------------------
// Kernel 1 (merged prep): blocks 0..1023 = rowsq + x h/l/q split;
// blocks 1024..1151 = weight transpose+split (both matrices).
// ---------------------------------------------------------------------------
__global__ __launch_bounds__(256) void prep_kernel(const float* __restrict__ x,
                                                   float* __restrict__ x2,
                                                   ushort* __restrict__ xhi,
                                                   ushort* __restrict__ xlo,
                                                   ushort* __restrict__ xqd,
                                                   const float* __restrict__ Wqkv,
                                                   const float* __restrict__ Wout,
                                                   ushort* __restrict__ wqhiT,
                                                   ushort* __restrict__ wqloT,
                                                   ushort* __restrict__ wohiT,
                                                   ushort* __restrict__ woloT) {
    __shared__ float tile[64][65];
    int gbid = blockIdx.x;
    if (gbid < PREP_BLOCKS) {
        int wave = threadIdx.x >> 6, lane = threadIdx.x & 63;
        int row = gbid * 4 + wave;
        const float* xr = x + (size_t)row * CDIM;
        float4 v = *(const float4*)(xr + lane * 4);
        float s = v.x*v.x + v.y*v.y + v.z*v.z + v.w*v.w;
        #pragma unroll
        for (int o = 32; o; o >>= 1) s += __shfl_down(s, o);
        if (lane == 0) x2[row] = s;

        ushort h[4], l[4], q[4];
        bfsplit3(v.x, &h[0], &l[0], &q[0]);
        bfsplit3(v.y, &h[1], &l[1], &q[1]);
        bfsplit3(v.z, &h[2], &l[2], &q[2]);
        bfsplit3(v.w, &h[3], &l[3], &q[3]);
        size_t off = (size_t)row * CDIM + lane * 4;
        *(ushort4v*)(xhi + off) = *(ushort4v*)h;
        *(ushort4v*)(xlo + off) = *(ushort4v*)l;
        *(ushort4v*)(xqd + off) = *(ushort4v*)q;
        return;
    }

    int bid = gbid - PREP_BLOCKS;
    const float* W; ushort* hiT; ushort* loT; int K, N, bx, by;
    if (bid < 96) { W = Wqkv; hiT = wqhiT; loT = wqloT; K = CDIM;  N = TRIPLE; bx = bid % 24; by = bid / 24; }
    else { int t = bid - 96; W = Wout; hiT = wohiT; loT = woloT; K = INNER; N = CDIM;  bx = t % 4;  by = t / 4; }
    int k0 = by * 64, n0 = bx * 64;
    #pragma unroll
    for (int i = 0; i < 4; ++i) {
        int f = threadIdx.x + i * 256;
        int r = f >> 4, c4 = (f & 15) * 4;
        float4 v = *(const float4*)(W + (size_t)(k0 + r) * N + n0 + c4);
        tile[r][c4+0] = v.x; tile[r][c4+1] = v.y;
        tile[r][c4+2] = v.z; tile[r][c4+3] = v.w;
    }
    __syncthreads();
    #pragma unroll
    for (int i = 0; i < 4; ++i) {
        int f = threadIdx.x + i * 256;
        int rn = f >> 4, ck = (f & 15) * 4;
        unsigned p0 = bfsplit(tile[ck+0][rn]);
        unsigned p1 = bfsplit(tile[ck+1][rn]);
        unsigned p2 = bfsplit(tile[ck+2][rn]);
        unsigned p3 = bfsplit(tile[ck+3][rn]);
        ushort4v h, l;
        h.x = (ushort)p0; l.x = (ushort)(p0 >> 16);
        h.y = (ushort)p1; l.y = (ushort)(p1 >> 16);
        h.z = (ushort)p2; l.z = (ushort)(p2 >> 16);
        h.w = (ushort)p3; l.w = (ushort)(p3 >> 16);
        *(ushort4v*)(hiT + (size_t)(n0 + rn) * K + k0 + ck) = h;
        *(ushort4v*)(loT + (size_t)(n0 + rn) * K + k0 + ck) = l;
    }
}

// ---------------------------------------------------------------------------
// MFMA bodies: register-staged global->LDS + linear TW=32 tiles with
// chunk-XOR swizzle -> conflict-free reads, compiler hoists prefetch.
// ---------------------------------------------------------------------------

// GEMM body (hi/lo, 3 products hh+hl+lh). Two output modes:
//  - qkv mode (kv16 != nullptr): cols <512 -> q fp32 [row][512];
//    cols >=512 -> kv16 fp16 [row][1024]. C holds q.
//  - plain mode: C[row*N+col] = acc + bias.
__device__ __forceinline__ void gemm_split_body(const ushort* __restrict__ Ahi,
                                                const ushort* __restrict__ Alo,
                                                const ushort* __restrict__ BhiT,
                                                const ushort* __restrict__ BloT,
                                                const float* __restrict__ bias,
                                                float* __restrict__ C,
                                                int N, int K, int bi, int bj,
                                                ushort* lds,
                                                ushort* __restrict__ kv16) {
    int lane = threadIdx.x & 63, wave = threadIdx.x >> 6;
    int wr = wave >> 1, wc = wave & 1;
    int fr = lane & 15, kg = lane >> 4;
    int swz8 = (kg ^ ((fr >> 1) & 3)) * 8;      // read-side chunk swizzle

    int srow = threadIdx.x >> 1;                // 0..127
    int hc = (threadIdx.x & 1) * 2;             // global chunk base: 0 or 2
    int sw = (srow >> 1) & 3;                   // row swizzle key
    int d0 = srow * TW + ((hc + 0) ^ sw) * 8;   // LDS dests (swizzled)
    int d1 = srow * TW + ((hc + 1) ^ sw) * 8;

    const ushort* g0 = Ahi  + (size_t)(bi + srow) * K + hc * 8;
    const ushort* g1 = Alo  + (size_t)(bi + srow) * K + hc * 8;
    const ushort* g2 = BhiT + (size_t)(bj + srow) * K + hc * 8;
    const ushort* g3 = BloT + (size_t)(bj + srow) * K + hc * 8;

    floatx4 acc[4][4] = {};

    for (int k0 = 0; k0 < K; k0 += 32) {
        uint4 va0 = *(const uint4*)(g0 + k0);
        uint4 va1 = *(const uint4*)(g0 + k0 + 8);
        uint4 vb0 = *(const uint4*)(g1 + k0);
        uint4 vb1 = *(const uint4*)(g1 + k0 + 8);
        uint4 vc0 = *(const uint4*)(g2 + k0);
        uint4 vc1 = *(const uint4*)(g2 + k0 + 8);
        uint4 vd0 = *(const uint4*)(g3 + k0);
        uint4 vd1 = *(const uint4*)(g3 + k0 + 8);
        *(uint4*)&lds[0*TSZ + d0] = va0;  *(uint4*)&lds[0*TSZ + d1] = va1;
        *(uint4*)&lds[1*TSZ + d0] = vb0;  *(uint4*)&lds[1*TSZ + d1] = vb1;
        *(uint4*)&lds[2*TSZ + d0] = vc0;  *(uint4*)&lds[2*TSZ + d1] = vc1;
        *(uint4*)&lds[3*TSZ + d0] = vd0;  *(uint4*)&lds[3*TSZ + d1] = vd1;
        __syncthreads();

        short8 a_h[4], a_l[4], b_h[4], b_l[4];
        #pragma unroll
        for (int m = 0; m < 4; ++m) {
            int off = (wr*64 + m*16 + fr) * TW + swz8;
            a_h[m] = *(const short8*)&lds[0*TSZ + off];
            a_l[m] = *(const short8*)&lds[1*TSZ + off];
        }
        #pragma unroll
        for (int n = 0; n < 4; ++n) {
            int off = (wc*64 + n*16 + fr) * TW + swz8;
            b_h[n] = *(const short8*)&lds[2*TSZ + off];
            b_l[n] = *(const short8*)&lds[3*TSZ + off];
        }
        #pragma unroll
        for (int m = 0; m < 4; ++m)
            #pragma unroll
            for (int n = 0; n < 4; ++n) {
                acc[m][n] = __builtin_amdgcn_mfma_f32_16x16x32_bf16(a_h[m], b_h[n], acc[m][n], 0, 0, 0);
                acc[m][n] = __builtin_amdgcn_mfma_f32_16x16x32_bf16(a_h[m], b_l[n], acc[m][n], 0, 0, 0);
                acc[m][n] = __builtin_amdgcn_mfma_f32_16x16x32_bf16(a_l[m], b_h[n], acc[m][n], 0, 0, 0);
            }
        __syncthreads();
    }

    if (kv16) {
        // qkv mode: q fp32 compact + k/v fp16 only (block cols are uniform)
        bool is_q = (bj < INNER);
        #pragma unroll
        for (int m = 0; m < 4; ++m)
            #pragma unroll
            for (int n = 0; n < 4; ++n) {
                int col = bj + wc*64 + n*16 + fr;
                #pragma unroll
                for (int r = 0; r < 4; ++r) {
                    int row = bi + wr*64 + m*16 + kg*4 + r;
                    float val = acc[m][n][r];
                    if (is_q) C[(size_t)row * INNER + col] = val;
                    else      kv16[(size_t)row * 1024 + (col - INNER)] = f2h(val);
                }
            }
    } else {
        #pragma unroll
        for (int m = 0; m < 4; ++m)
            #pragma unroll
            for (int n = 0; n < 4; ++n) {
                int col = bj + wc*64 + n*16 + fr;
                float bv = bias ? bias[col] : 0.0f;
                #pragma unroll
                for (int r = 0; r < 4; ++r) {
                    int row = bi + wr*64 + m*16 + kg*4 + r;
                    C[(size_t)row * N + col] = acc[m][n][r] + bv;
                }
            }
    }
}

// Gram body: 3-split, 6 products (fp32-precision, selection-safe).
// Computes tile (bi,bj); if bi!=bj also mirror-writes (bj,bi) via LDS
// transpose (dot symmetric; MFMA sum order identical -> bit-identical).
__device__ __forceinline__ void gram_body(const ushort* __restrict__ Ah,
                                          const ushort* __restrict__ Al,
                                          const ushort* __restrict__ Aq,
                                          const float* __restrict__ x2b,
                                          float* __restrict__ Sb,
                                          int bi, int bj, ushort* lds) {
    int lane = threadIdx.x & 63, wave = threadIdx.x >> 6;
    int wr = wave >> 1, wc = wave & 1;
    int fr = lane & 15, kg = lane >> 4;
    int swz8 = (kg ^ ((fr >> 1) & 3)) * 8;

    int srow = threadIdx.x >> 1;
    int hc = (threadIdx.x & 1) * 2;
    int sw = (srow >> 1) & 3;
    int d0 = srow * TW + ((hc + 0) ^ sw) * 8;
    int d1 = srow * TW + ((hc + 1) ^ sw) * 8;

    const ushort* g0 = Ah + (size_t)(bi + srow) * CDIM + hc * 8;
    const ushort* g1 = Al + (size_t)(bi + srow) * CDIM + hc * 8;
    const ushort* g2 = Aq + (size_t)(bi + srow) * CDIM + hc * 8;
    const ushort* g3 = Ah + (size_t)(bj + srow) * CDIM + hc * 8;
    const ushort* g4 = Al + (size_t)(bj + srow) * CDIM + hc * 8;
    const ushort* g5 = Aq + (size_t)(bj + srow) * CDIM + hc * 8;

    floatx4 acc[4][4] = {};

    for (int k0 = 0; k0 < CDIM; k0 += 32) {
        uint4 a0 = *(const uint4*)(g0 + k0); uint4 a1 = *(const uint4*)(g0 + k0 + 8);
        uint4 b0 = *(const uint4*)(g1 + k0); uint4 b1 = *(const uint4*)(g1 + k0 + 8);
        uint4 c0 = *(const uint4*)(g2 + k0); uint4 c1 = *(const uint4*)(g2 + k0 + 8);
        uint4 e0 = *(const uint4*)(g3 + k0); uint4 e1 = *(const uint4*)(g3 + k0 + 8);
        uint4 f0 = *(const uint4*)(g4 + k0); uint4 f1 = *(const uint4*)(g4 + k0 + 8);
        uint4 h0 = *(const uint4*)(g5 + k0); uint4 h1 = *(const uint4*)(g5 + k0 + 8);
        *(uint4*)&lds[0*TSZ + d0] = a0; *(uint4*)&lds[0*TSZ + d1] = a1;
        *(uint4*)&lds[1*TSZ + d0] = b0; *(uint4*)&lds[1*TSZ + d1] = b1;
        *(uint4*)&lds[2*TSZ + d0] = c0; *(uint4*)&lds[2*TSZ + d1] = c1;
        *(uint4*)&lds[3*TSZ + d0] = e0; *(uint4*)&lds[3*TSZ + d1] = e1;
        *(uint4*)&lds[4*TSZ + d0] = f0; *(uint4*)&lds[4*TSZ + d1] = f1;
        *(uint4*)&lds[5*TSZ + d0] = h0; *(uint4*)&lds[5*TSZ + d1] = h1;
        __syncthreads();

        short8 a_h[4], a_l[4], a_q[4], b_h[4], b_l[4], b_q[4];
        #pragma unroll
        for (int m = 0; m < 4; ++m) {
            int off = (wr*64 + m*16 + fr) * TW + swz8;
            a_h[m] = *(const short8*)&lds[0*TSZ + off];
            a_l[m] = *(const short8*)&lds[1*TSZ + off];
            a_q[m] = *(const short8*)&lds[2*TSZ + off];
        }
        #pragma unroll
        for (int n = 0; n < 4; ++n) {
            int off = (wc*64 + n*16 + fr) * TW + swz8;
            b_h[n] = *(const short8*)&lds[3*TSZ + off];
            b_l[n] = *(const short8*)&lds[4*TSZ + off];
            b_q[n] = *(const short8*)&lds[5*TSZ + off];
        }
        #pragma unroll
        for (int m = 0; m < 4; ++m)
            #pragma unroll
            for (int n = 0; n < 4; ++n) {
                acc[m][n] = __builtin_amdgcn_mfma_f32_16x16x32_bf16(a_h[m], b_h[n], acc[m][n], 0, 0, 0);
                acc[m][n] = __builtin_amdgcn_mfma_f32_16x16x32_bf16(a_h[m], b_l[n], acc[m][n], 0, 0, 0);
                acc[m][n] = __builtin_amdgcn_mfma_f32_16x16x32_bf16(a_l[m], b_h[n], acc[m][n], 0, 0, 0);
                acc[m][n] = __builtin_amdgcn_mfma_f32_16x16x32_bf16(a_l[m], b_l[n], acc[m][n], 0, 0, 0);
                acc[m][n] = __builtin_amdgcn_mfma_f32_16x16x32_bf16(a_h[m], b_q[n], acc[m][n], 0, 0, 0);
                acc[m][n] = __builtin_amdgcn_mfma_f32_16x16x32_bf16(a_q[m], b_h[n], acc[m][n], 0, 0, 0);
            }
        __syncthreads();
    }

    // normal write: S[bi+row][bj+col] = x2[col] - 2 acc (diag -> inf)
    #pragma unroll
    for (int m = 0; m < 4; ++m)
        #pragma unroll
        for (int n = 0; n < 4; ++n) {
            int col = bj + wc*64 + n*16 + fr;
            float xc = x2b[col];
            #pragma unroll
            for (int r = 0; r < 4; ++r) {
                int row = bi + wr*64 + m*16 + kg*4 + r;
                float val = xc - 2.0f * acc[m][n][r];
                if (row == col) val = __builtin_inff();
                Sb[(size_t)row * NPTS + col] = val;
            }
        }

    // mirror write: S[bj+col][bi+row] = x2[row] - 2 acc, via LDS transpose
    if (bi != bj) {
        float* T = (float*)lds;                 // 64 x 128, stride 132 floats
        #pragma unroll
        for (int p = 0; p < 2; ++p) {
            __syncthreads();
            if (wc == p) {
                #pragma unroll
                for (int m = 0; m < 4; ++m) {
                    int row0 = wr*64 + m*16 + kg*4;
                    float x0 = x2b[bi + row0 + 0];
                    float x1 = x2b[bi + row0 + 1];
                    float x2v = x2b[bi + row0 + 2];
                    float x3 = x2b[bi + row0 + 3];
                    #pragma unroll
                    for (int n = 0; n < 4; ++n) {
                        int colp = n*16 + fr;   // 0..63 within pass
                        float4 v;
                        v.x = x0 - 2.0f * acc[m][n][0];
                        v.y = x1 - 2.0f * acc[m][n][1];
                        v.z = x2v - 2.0f * acc[m][n][2];
                        v.w = x3 - 2.0f * acc[m][n][3];
                        *(float4*)&T[colp * 132 + row0] = v;
                    }
                }
            }
            __syncthreads();
            #pragma unroll
            for (int i = 0; i < 8; ++i) {
                int f = threadIdx.x + i * 256;  // 0..2047
                int cr = f >> 5, c4 = (f & 31) * 4;
                float4 v = *(const float4*)&T[cr * 132 + c4];
                *(float4*)(Sb + (size_t)(bj + p*64 + cr) * NPTS + bi + c4) = v;
            }
        }
    }
}

// ---------------------------------------------------------------------------
// Kernel 2: static-grid MFMA kernel, sequential item order (best measured).
// Items 0..271 gram, 272..655 qkv (q fp32 + k/v fp16 emit).
// ---------------------------------------------------------------------------
__global__ __launch_bounds__(256) void fused_mfma_kernel(const ushort* __restrict__ xh,
                                                         const ushort* __restrict__ xl,
                                                         const ushort* __restrict__ xq,
                                                         const float* __restrict__ x2,
                                                         float* __restrict__ S,
                                                         const ushort* __restrict__ wqhiT,
                                                         const ushort* __restrict__ wqloT,
                                                         float* __restrict__ q,
                                                         ushort* __restrict__ kv16) {
    __shared__ ushort lds[6*TSZ];    // 48 KB -> 3 blocks/CU
    int item = blockIdx.x;
    if (item < GRAM_ITEMS) {
        int b = item / 136, t = item % 136;
        int by = 0;
        while (t >= 16 - by) { t -= 16 - by; ++by; }
        int bx = by + t;                 // by <= bx (upper triangle)
        size_t xoff = (size_t)b * NPTS * CDIM;
        gram_body(xh + xoff, xl + xoff, xq + xoff,
                  x2 + (size_t)b * NPTS, S + (size_t)b * NPTS * NPTS,
                  by * 128, bx * 128, lds);
    } else {
        int t = item - GRAM_ITEMS;       // 0..383
        int bx = t % 12, by = t / 12;
        gemm_split_body(xh, xl, wqhiT, wqloT, nullptr, q,
                        TRIPLE, CDIM, by * 128, bx * 128, lds, kv16);
    }
}

// ---------------------------------------------------------------------------
// Kernel 3: out projection (staged split GEMM + bias).
// ---------------------------------------------------------------------------
__global__ __launch_bounds__(256) void outproj_kernel(const ushort* __restrict__ Ahi,
                                                      const ushort* __restrict__ Alo,
                                                      const ushort* __restrict__ BhiT,
                                                      const ushort* __restrict__ BloT,
                                                      const float* __restrict__ bias,
                                                      float* __restrict__ C) {
    __shared__ ushort lds[4*TSZ];    // 32 KB
    gemm_split_body(Ahi, Alo, BhiT, BloT, bias, C,
                    CDIM, INNER, blockIdx.y * 128, blockIdx.x * 128, lds, nullptr);
}

// ---------------------------------------------------------------------------
// Kernel 4 (fused): top-KNN selection + sparse attention, one block per (b,n).
// ---------------------------------------------------------------------------
__device__ __forceinline__ unsigned block_excl_scan_256(unsigned c,
                                                        unsigned* wsum,
                                                        unsigned* total_out) {
    unsigned v = c;
    #pragma unroll
    for (int o = 1; o < 64; o <<= 1) {
        unsigned t = __shfl_up(v, o);
        if ((threadIdx.x & 63) >= o) v += t;
    }
    if ((threadIdx.x & 63) == 63) wsum[threadIdx.x >> 6] = v;
    __syncthreads();
    unsigned woff = 0;
    int mywave = threadIdx.x >> 6;
    #pragma unroll
    for (int w = 0; w < 4; ++w) {
        unsigned s = wsum[w];
        if (w < mywave) woff += s;
    }
    if (total_out) *total_out = wsum[0] + wsum[1] + wsum[2] + wsum[3];
    __syncthreads();
    return v + woff - c;
}

__global__ __launch_bounds__(256) void knn_attn_kernel(const float* __restrict__ S,
                                                       const float* __restrict__ q,
                                                       const ushort* __restrict__ kv16,
                                                       ushort* __restrict__ ahi,
                                                       ushort* __restrict__ alo) {
    int bid = blockIdx.x;
    int b = (bid & 7) >> 2;
    int n = ((bid >> 3) << 2) | (bid & 3);
    size_t rowoff = (size_t)b * NPTS + n;
    const float* row = S + rowoff * NPTS;

    __shared__ unsigned keys[NPTS];
    __shared__ unsigned hist[256];
    __shared__ unsigned wsum[4];
    __shared__ unsigned s_red[8];
    __shared__ unsigned sh_lo, sh_hi, sh_rank, sh_cnt, sh_break;
    __shared__ unsigned ckey[64];
    __shared__ int     cidx[64];
    __shared__ unsigned s_ccount;
    __shared__ int   nb[KNN];
    __shared__ float dots[NHEAD][KNN];
    __shared__ float p[NHEAD][KNN];

    int tid = threadIdx.x;

    // ---- selection phase ----
    unsigned mn = 0xffffffffu, mx = 0u;
    {
        int i0 = tid * 8;
        float4 f0 = *(const float4*)(row + i0);
        float4 f1 = *(const float4*)(row + i0 + 4);
        float fv[8] = { f0.x, f0.y, f0.z, f0.w, f1.x, f1.y, f1.z, f1.w };
        #pragma unroll
        for (int t = 0; t < 8; ++t) {
            int i = i0 + t;
            unsigned u;
            if (i == n) {
                u = 0xffffffffu;
            } else {
                unsigned v = __float_as_uint(fv[t]);
                u = (v & 0x80000000u) ? ~v : (v | 0x80000000u);
                mn = min(mn, u); mx = max(mx, u);
            }
            keys[i] = u;
        }
    }
    #pragma unroll
    for (int o = 32; o; o >>= 1) {
        mn = min(mn, (unsigned)__shfl_xor((int)mn, o));
        mx = max(mx, (unsigned)__shfl_xor((int)mx, o));
    }
    if ((tid & 63) == 0) { s_red[tid >> 6] = mn; s_red[4 + (tid >> 6)] = mx; }
    __syncthreads();
    if (tid == 0) {
        unsigned a = min(min(s_red[0], s_red[1]), min(s_red[2], s_red[3]));
        unsigned z = max(max(s_red[4], s_red[5]), max(s_red[6], s_red[7]));
        sh_lo = a; sh_hi = z; sh_rank = KNN; sh_break = 0; s_ccount = 0;
    }
    __syncthreads();

    for (int it = 0; it < 5; ++it) {
        unsigned lo = sh_lo, hi = sh_hi;
        unsigned range1 = hi - lo;
        int shift = 0;
        if (range1 > 255u) shift = 24 - __clz(range1);
        hist[tid] = 0;
        __syncthreads();
        for (int i = tid; i < NPTS; i += 256) {
            unsigned u = keys[i];
            if (u >= lo && u <= hi)
                atomicAdd(&hist[(u - lo) >> shift], 1u);
        }
        __syncthreads();
        unsigned c = hist[tid];
        unsigned rank = sh_rank;
        unsigned excl = block_excl_scan_256(c, wsum, nullptr);
        if (excl < rank && excl + c >= rank) {
            sh_rank = rank - excl;
            unsigned nlo = lo + ((unsigned)tid << shift);
            unsigned span = (shift == 0) ? 0u : (((1u << shift)) - 1u);
            unsigned nhi = nlo + span;
            if (nhi > hi || nhi < nlo) nhi = hi;
            sh_lo = nlo; sh_hi = nhi;
            sh_cnt = c;
            sh_break = (shift == 0 || c <= 64u) ? 1u : 0u;
        }
        __syncthreads();
        if (sh_break) break;
    }

    unsigned lo = sh_lo, hi = sh_hi, rank = sh_rank, cnt = sh_cnt;

    unsigned lt = 0;
    for (int i = tid; i < NPTS; i += 256) lt += (keys[i] < lo) ? 1u : 0u;
    unsigned pos = block_excl_scan_256(lt, wsum, nullptr);
    for (int i = tid; i < NPTS; i += 256) {
        unsigned u = keys[i];
        if (u < lo) nb[pos++] = i;
        else if (u >= lo && u <= hi && cnt <= 64u) {
            unsigned pp = atomicAdd(&s_ccount, 1u);
            ckey[pp] = u; cidx[pp] = i;
        }
    }
    __syncthreads();

    unsigned base = KNN - rank;
    if (cnt <= 64u) {
        if (tid < (int)cnt) {
            unsigned myk = ckey[tid]; int myi = cidx[tid];
            unsigned r = 0;
            for (unsigned s = 0; s < cnt; ++s) {
                unsigned sk = ckey[s]; int si = cidx[s];
                r += (sk < myk || (sk == myk && si < myi)) ? 1u : 0u;
            }
            if (r < rank) nb[base + r] = myi;
        }
    } else {
        if (tid == 0) {
            unsigned need = rank, pp = base;
            for (int i = 0; i < NPTS && need; ++i) {
                if (keys[i] >= lo && keys[i] <= hi) { nb[pp++] = i; --need; }
            }
        }
    }
    __syncthreads();

    // ---- attention phase (fp16 K/V gather, fp32 math) ----
    const float* qrow = q + rowoff * INNER;
    const ushort* kvb = kv16 + (size_t)b * NPTS * 1024;

    // phase 1: dots
    {
        int j = tid >> 3;              // neighbor 0..31
        int l = tid & 7;               // 8-elem segment 0..7
        const ushort* krow = kvb + (size_t)nb[j] * 1024 + l * 8;   // k at 0..511
        short8 kr[NHEAD];
        #pragma unroll
        for (int h = 0; h < NHEAD; ++h)
            kr[h] = *(const short8*)(krow + h * DHEAD);
        const float* qp = qrow + l * 8;
        #pragma unroll
        for (int h = 0; h < NHEAD; ++h) {
            float4 q0 = *(const float4*)(qp + h * DHEAD);
            float4 q1 = *(const float4*)(qp + h * DHEAD + 4);
            float d = h2f((ushort)kr[h][0]) * q0.x + h2f((ushort)kr[h][1]) * q0.y
                    + h2f((ushort)kr[h][2]) * q0.z + h2f((ushort)kr[h][3]) * q0.w
                    + h2f((ushort)kr[h][4]) * q1.x + h2f((ushort)kr[h][5]) * q1.y
                    + h2f((ushort)kr[h][6]) * q1.z + h2f((ushort)kr[h][7]) * q1.w;
            d += __shfl_xor(d, 1);
            d += __shfl_xor(d, 2);
            d += __shfl_xor(d, 4);
            if (l == 0) dots[h][j] = d * SCALE;
        }
    }
    __syncthreads();

    // phase 1b: softmax per head
    {
        int h = tid >> 5, jj = tid & 31;
        float dv = dots[h][jj];
        float mxv = dv;
        for (int o = 16; o; o >>= 1) mxv = fmaxf(mxv, __shfl_xor(mxv, o));
        float e = expf(dv - mxv);
        float s = e;
        for (int o = 16; o; o >>= 1) s += __shfl_xor(s, o);
        p[h][jj] = e / s;
    }
    __syncthreads();

    // phase 2: weighted V sum (fp16 V), 8 loads in flight per group
    {
        int hd = tid >> 5;
        int jd = tid & 31;
        const ushort* vb = kvb + INNER + hd * DHEAD + jd * 2;      // v at 512..1023
        float o0 = 0.f, o1 = 0.f;
        #pragma unroll
        for (int g = 0; g < 4; ++g) {
            unsigned vv[8]; float pw[8];
            #pragma unroll
            for (int t = 0; t < 8; ++t) {
                int jj = g * 8 + t;
                vv[t] = *(const unsigned*)(vb + (size_t)nb[jj] * 1024);
                pw[t] = p[hd][jj];
            }
            #pragma unroll
            for (int t = 0; t < 8; ++t) {
                o0 += pw[t] * h2f((ushort)(vv[t] & 0xffffu));
                o1 += pw[t] * h2f((ushort)(vv[t] >> 16));
            }
        }
        size_t baseo = rowoff * INNER + hd * DHEAD + jd * 2;
        unsigned q0 = bfsplit(o0);
        unsigned q1 = bfsplit(o1);
        *(unsigned*)(ahi + baseo) = (q0 & 0xffffu) | (q1 << 16);
        *(unsigned*)(alo + baseo) = (q0 >> 16) | (q1 & 0xffff0000u);
    }
}

// ---------------------------------------------------------------------------
extern "C" void kernel_launch(void* const* d_in, const int* in_sizes, int n_in,
                              void* d_out, int out_size, void* d_ws, size_t ws_size,
                              hipStream_t stream) {
    const float* x    = (const float*)d_in[0];   // [2,2048,256]
    const float* Wqkv = (const float*)d_in[1];   // [256,1536]
    const float* Wout = (const float*)d_in[2];   // [512,256]
    const float* bout = (const float*)d_in[3];   // [256]
    float* out = (float*)d_out;                  // [2,2048,256]

    // workspace layout
    float* S     = (float*)d_ws;                           // B*N*N f32
    float* x2    = S + (size_t)BATCH * NPTS * NPTS;        // B*N f32
    float* q     = x2 + (size_t)BATCH * NPTS;              // B*N*512 f32
    ushort* kv16 = (ushort*)(q + (size_t)BATCH * NPTS * INNER); // B*N*1024 fp16
    ushort* xhi  = kv16 + (size_t)BATCH * NPTS * 1024;
    ushort* xlo   = xhi   + (size_t)BATCH * NPTS * CDIM;
    ushort* xqd   = xlo   + (size_t)BATCH * NPTS * CDIM;
    ushort* ahi   = xqd   + (size_t)BATCH * NPTS * CDIM;
    ushort* alo   = ahi   + (size_t)BATCH * NPTS * INNER;
    ushort* wqhiT = alo   + (size_t)BATCH * NPTS * INNER;  // [1536][256]
    ushort* wqloT = wqhiT + (size_t)TRIPLE * CDIM;
    ushort* wohiT = wqloT + (size_t)TRIPLE * CDIM;         // [256][512]
    ushort* woloT = wohiT + (size_t)CDIM * INNER;

    // 1. merged prep: rowsq + x split + weight transposes
    prep_kernel<<<PREP_BLOCKS + WT_BLOCKS, 256, 0, stream>>>(
        x, x2, xhi, xlo, xqd, Wqkv, Wout, wqhiT, wqloT, wohiT, woloT);

    // 2. static gram (upper-tri + mirror) + qkv GEMM, sequential item order
    fused_mfma_kernel<<<TOTAL_ITEMS, 256, 0, stream>>>(xhi, xlo, xqd, x2, S,
                                                       wqhiT, wqloT, q, kv16);

    // 3. fused top-32 selection + sparse attention (XCD batch pinning)
    knn_attn_kernel<<<BATCH * NPTS, 256, 0, stream>>>(S, q, kv16, ahi, alo);

    // 4. output projection: [4096,512] @ [512,256] + bias
    {
        dim3 grid(CDIM / 128, (BATCH * NPTS) / 128);
        outproj_kernel<<<grid, 256, 0, stream>>>(ahi, alo, wohiT, woloT, bout, out);
    }
}

// Round 19
// 103.308 us; speedup vs baseline: 1.4508x; 1.0095x over previous
//
#include <hip/hip_runtime.h>
#include <hip/hip_bf16.h>
#include <hip/hip_fp16.h>

// Problem constants
#define BATCH 2
#define NPTS  2048
#define CDIM  256
#define NHEAD 8
#define DHEAD 64
#define INNER 512            // NHEAD*DHEAD
#define TRIPLE 1536          // 3*INNER
#define KNN   32
#define SCALE 0.125f         // 64^-0.5

#define GRAM_ITEMS 272       // 2 batches x 136 upper-tri 128x128 tiles
#define QKV_ITEMS  384       // 32 row-tiles x 12 col-tiles
#define TOTAL_ITEMS (GRAM_ITEMS + QKV_ITEMS)   // 656

#define PREP_BLOCKS 1024     // 4096 rows / 4 rows-per-block
#define WT_BLOCKS   128

typedef __attribute__((ext_vector_type(8))) short short8;      // 8 bf16 (4 VGPR)
typedef __attribute__((ext_vector_type(4))) float floatx4;     // MFMA acc
typedef __attribute__((ext_vector_type(4))) unsigned short ushort4v;
typedef unsigned short ushort;

#define TW  32               // LDS tile row width in ushort (64 B, linear)
#define TSZ (128*TW)         // ushorts per 128-row tile (8192 B)

// bf16 split: x = hi + lo (both RNE bf16). hi in [15:0], lo in [31:16].
__device__ __forceinline__ unsigned bfsplit(float x) {
    unsigned u = __float_as_uint(x);
    unsigned r = u + 0x7fffu + ((u >> 16) & 1u);
    unsigned hs = r >> 16;
    float hf = __uint_as_float(hs << 16);
    float lo = x - hf;
    unsigned u2 = __float_as_uint(lo);
    unsigned r2 = u2 + 0x7fffu + ((u2 >> 16) & 1u);
    return (hs & 0xffffu) | (r2 & 0xffff0000u);
}

// 3-component split: x = h + l + q, residual ~2^-27 relative.
__device__ __forceinline__ void bfsplit3(float x, ushort* hh, ushort* ll, ushort* qq) {
    unsigned u = __float_as_uint(x);
    unsigned r = u + 0x7fffu + ((u >> 16) & 1u);
    unsigned hs = r >> 16;
    float hf = __uint_as_float(hs << 16);
    float d1 = x - hf;
    unsigned u2 = __float_as_uint(d1);
    unsigned r2 = u2 + 0x7fffu + ((u2 >> 16) & 1u);
    unsigned ls = r2 >> 16;
    float lf = __uint_as_float(ls << 16);
    float d2 = d1 - lf;
    unsigned u3 = __float_as_uint(d2);
    unsigned r3 = u3 + 0x7fffu + ((u3 >> 16) & 1u);
    *hh = (ushort)hs;
    *ll = (ushort)ls;
    *qq = (ushort)(r3 >> 16);
}

// fp16 bit helpers
__device__ __forceinline__ ushort f2h(float f) {
    __half h = __float2half(f);               // RNE
    return *reinterpret_cast<ushort*>(&h);
}
__device__ __forceinline__ float h2f(ushort u) {
    __half h;
    *reinterpret_cast<ushort*>(&h) = u;
    return __half2float(h);
}

// ---------------------------------------------------------------------------
// Kernel 1 (merged prep): blocks 0..1023 = rowsq + x h/l/q split;
// blocks 1024..1151 = weight transpose+split (both matrices).
// ---------------------------------------------------------------------------
__global__ __launch_bounds__(256) void prep_kernel(const float* __restrict__ x,
                                                   float* __restrict__ x2,
                                                   ushort* __restrict__ xhi,
                                                   ushort* __restrict__ xlo,
                                                   ushort* __restrict__ xqd,
                                                   const float* __restrict__ Wqkv,
                                                   const float* __restrict__ Wout,
                                                   ushort* __restrict__ wqhiT,
                                                   ushort* __restrict__ wqloT,
                                                   ushort* __restrict__ wohiT,
                                                   ushort* __restrict__ woloT) {
    __shared__ float tile[64][65];
    int gbid = blockIdx.x;
    if (gbid < PREP_BLOCKS) {
        int wave = threadIdx.x >> 6, lane = threadIdx.x & 63;
        int row = gbid * 4 + wave;
        const float* xr = x + (size_t)row * CDIM;
        float4 v = *(const float4*)(xr + lane * 4);
        float s = v.x*v.x + v.y*v.y + v.z*v.z + v.w*v.w;
        #pragma unroll
        for (int o = 32; o; o >>= 1) s += __shfl_down(s, o);
        if (lane == 0) x2[row] = s;

        ushort h[4], l[4], q[4];
        bfsplit3(v.x, &h[0], &l[0], &q[0]);
        bfsplit3(v.y, &h[1], &l[1], &q[1]);
        bfsplit3(v.z, &h[2], &l[2], &q[2]);
        bfsplit3(v.w, &h[3], &l[3], &q[3]);
        size_t off = (size_t)row * CDIM + lane * 4;
        *(ushort4v*)(xhi + off) = *(ushort4v*)h;
        *(ushort4v*)(xlo + off) = *(ushort4v*)l;
        *(ushort4v*)(xqd + off) = *(ushort4v*)q;
        return;
    }

    int bid = gbid - PREP_BLOCKS;
    const float* W; ushort* hiT; ushort* loT; int K, N, bx, by;
    if (bid < 96) { W = Wqkv; hiT = wqhiT; loT = wqloT; K = CDIM;  N = TRIPLE; bx = bid % 24; by = bid / 24; }
    else { int t = bid - 96; W = Wout; hiT = wohiT; loT = woloT; K = INNER; N = CDIM;  bx = t % 4;  by = t / 4; }
    int k0 = by * 64, n0 = bx * 64;
    #pragma unroll
    for (int i = 0; i < 4; ++i) {
        int f = threadIdx.x + i * 256;
        int r = f >> 4, c4 = (f & 15) * 4;
        float4 v = *(const float4*)(W + (size_t)(k0 + r) * N + n0 + c4);
        tile[r][c4+0] = v.x; tile[r][c4+1] = v.y;
        tile[r][c4+2] = v.z; tile[r][c4+3] = v.w;
    }
    __syncthreads();
    #pragma unroll
    for (int i = 0; i < 4; ++i) {
        int f = threadIdx.x + i * 256;
        int rn = f >> 4, ck = (f & 15) * 4;
        unsigned p0 = bfsplit(tile[ck+0][rn]);
        unsigned p1 = bfsplit(tile[ck+1][rn]);
        unsigned p2 = bfsplit(tile[ck+2][rn]);
        unsigned p3 = bfsplit(tile[ck+3][rn]);
        ushort4v h, l;
        h.x = (ushort)p0; l.x = (ushort)(p0 >> 16);
        h.y = (ushort)p1; l.y = (ushort)(p1 >> 16);
        h.z = (ushort)p2; l.z = (ushort)(p2 >> 16);
        h.w = (ushort)p3; l.w = (ushort)(p3 >> 16);
        *(ushort4v*)(hiT + (size_t)(n0 + rn) * K + k0 + ck) = h;
        *(ushort4v*)(loT + (size_t)(n0 + rn) * K + k0 + ck) = l;
    }
}

// ---------------------------------------------------------------------------
// MFMA bodies: register-staged global->LDS + linear TW=32 tiles with
// chunk-XOR swizzle -> conflict-free reads, compiler hoists prefetch.
// ---------------------------------------------------------------------------

// GEMM body (hi/lo, 3 products hh+hl+lh). Two output modes:
//  - qkv mode (kv16 != nullptr): cols <512 -> q fp32 [row][512];
//    cols >=512 -> kv16 fp16 [row][1024]. C holds q.
//  - plain mode: C[row*N+col] = acc + bias.
__device__ __forceinline__ void gemm_split_body(const ushort* __restrict__ Ahi,
                                                const ushort* __restrict__ Alo,
                                                const ushort* __restrict__ BhiT,
                                                const ushort* __restrict__ BloT,
                                                const float* __restrict__ bias,
                                                float* __restrict__ C,
                                                int N, int K, int bi, int bj,
                                                ushort* lds,
                                                ushort* __restrict__ kv16) {
    int lane = threadIdx.x & 63, wave = threadIdx.x >> 6;
    int wr = wave >> 1, wc = wave & 1;
    int fr = lane & 15, kg = lane >> 4;
    int swz8 = (kg ^ ((fr >> 1) & 3)) * 8;      // read-side chunk swizzle

    int srow = threadIdx.x >> 1;                // 0..127
    int hc = (threadIdx.x & 1) * 2;             // global chunk base: 0 or 2
    int sw = (srow >> 1) & 3;                   // row swizzle key
    int d0 = srow * TW + ((hc + 0) ^ sw) * 8;   // LDS dests (swizzled)
    int d1 = srow * TW + ((hc + 1) ^ sw) * 8;

    const ushort* g0 = Ahi  + (size_t)(bi + srow) * K + hc * 8;
    const ushort* g1 = Alo  + (size_t)(bi + srow) * K + hc * 8;
    const ushort* g2 = BhiT + (size_t)(bj + srow) * K + hc * 8;
    const ushort* g3 = BloT + (size_t)(bj + srow) * K + hc * 8;

    floatx4 acc[4][4] = {};

    for (int k0 = 0; k0 < K; k0 += 32) {
        uint4 va0 = *(const uint4*)(g0 + k0);
        uint4 va1 = *(const uint4*)(g0 + k0 + 8);
        uint4 vb0 = *(const uint4*)(g1 + k0);
        uint4 vb1 = *(const uint4*)(g1 + k0 + 8);
        uint4 vc0 = *(const uint4*)(g2 + k0);
        uint4 vc1 = *(const uint4*)(g2 + k0 + 8);
        uint4 vd0 = *(const uint4*)(g3 + k0);
        uint4 vd1 = *(const uint4*)(g3 + k0 + 8);
        *(uint4*)&lds[0*TSZ + d0] = va0;  *(uint4*)&lds[0*TSZ + d1] = va1;
        *(uint4*)&lds[1*TSZ + d0] = vb0;  *(uint4*)&lds[1*TSZ + d1] = vb1;
        *(uint4*)&lds[2*TSZ + d0] = vc0;  *(uint4*)&lds[2*TSZ + d1] = vc1;
        *(uint4*)&lds[3*TSZ + d0] = vd0;  *(uint4*)&lds[3*TSZ + d1] = vd1;
        __syncthreads();

        short8 a_h[4], a_l[4], b_h[4], b_l[4];
        #pragma unroll
        for (int m = 0; m < 4; ++m) {
            int off = (wr*64 + m*16 + fr) * TW + swz8;
            a_h[m] = *(const short8*)&lds[0*TSZ + off];
            a_l[m] = *(const short8*)&lds[1*TSZ + off];
        }
        #pragma unroll
        for (int n = 0; n < 4; ++n) {
            int off = (wc*64 + n*16 + fr) * TW + swz8;
            b_h[n] = *(const short8*)&lds[2*TSZ + off];
            b_l[n] = *(const short8*)&lds[3*TSZ + off];
        }
        #pragma unroll
        for (int m = 0; m < 4; ++m)
            #pragma unroll
            for (int n = 0; n < 4; ++n) {
                acc[m][n] = __builtin_amdgcn_mfma_f32_16x16x32_bf16(a_h[m], b_h[n], acc[m][n], 0, 0, 0);
                acc[m][n] = __builtin_amdgcn_mfma_f32_16x16x32_bf16(a_h[m], b_l[n], acc[m][n], 0, 0, 0);
                acc[m][n] = __builtin_amdgcn_mfma_f32_16x16x32_bf16(a_l[m], b_h[n], acc[m][n], 0, 0, 0);
            }
        __syncthreads();
    }

    if (kv16) {
        // qkv mode: q fp32 compact + k/v fp16 only (block cols are uniform)
        bool is_q = (bj < INNER);
        #pragma unroll
        for (int m = 0; m < 4; ++m)
            #pragma unroll
            for (int n = 0; n < 4; ++n) {
                int col = bj + wc*64 + n*16 + fr;
                #pragma unroll
                for (int r = 0; r < 4; ++r) {
                    int row = bi + wr*64 + m*16 + kg*4 + r;
                    float val = acc[m][n][r];
                    if (is_q) C[(size_t)row * INNER + col] = val;
                    else      kv16[(size_t)row * 1024 + (col - INNER)] = f2h(val);
                }
            }
    } else {
        #pragma unroll
        for (int m = 0; m < 4; ++m)
            #pragma unroll
            for (int n = 0; n < 4; ++n) {
                int col = bj + wc*64 + n*16 + fr;
                float bv = bias ? bias[col] : 0.0f;
                #pragma unroll
                for (int r = 0; r < 4; ++r) {
                    int row = bi + wr*64 + m*16 + kg*4 + r;
                    C[(size_t)row * N + col] = acc[m][n][r] + bv;
                }
            }
    }
}

// Gram body: 3-split, 6 products (fp32-precision, selection-safe).
// Computes tile (bi,bj); if bi!=bj also mirror-writes (bj,bi) via LDS
// transpose (dot symmetric; MFMA sum order identical -> bit-identical).
__device__ __forceinline__ void gram_body(const ushort* __restrict__ Ah,
                                          const ushort* __restrict__ Al,
                                          const ushort* __restrict__ Aq,
                                          const float* __restrict__ x2b,
                                          float* __restrict__ Sb,
                                          int bi, int bj, ushort* lds) {
    int lane = threadIdx.x & 63, wave = threadIdx.x >> 6;
    int wr = wave >> 1, wc = wave & 1;
    int fr = lane & 15, kg = lane >> 4;
    int swz8 = (kg ^ ((fr >> 1) & 3)) * 8;

    int srow = threadIdx.x >> 1;
    int hc = (threadIdx.x & 1) * 2;
    int sw = (srow >> 1) & 3;
    int d0 = srow * TW + ((hc + 0) ^ sw) * 8;
    int d1 = srow * TW + ((hc + 1) ^ sw) * 8;

    const ushort* g0 = Ah + (size_t)(bi + srow) * CDIM + hc * 8;
    const ushort* g1 = Al + (size_t)(bi + srow) * CDIM + hc * 8;
    const ushort* g2 = Aq + (size_t)(bi + srow) * CDIM + hc * 8;
    const ushort* g3 = Ah + (size_t)(bj + srow) * CDIM + hc * 8;
    const ushort* g4 = Al + (size_t)(bj + srow) * CDIM + hc * 8;
    const ushort* g5 = Aq + (size_t)(bj + srow) * CDIM + hc * 8;

    floatx4 acc[4][4] = {};

    for (int k0 = 0; k0 < CDIM; k0 += 32) {
        uint4 a0 = *(const uint4*)(g0 + k0); uint4 a1 = *(const uint4*)(g0 + k0 + 8);
        uint4 b0 = *(const uint4*)(g1 + k0); uint4 b1 = *(const uint4*)(g1 + k0 + 8);
        uint4 c0 = *(const uint4*)(g2 + k0); uint4 c1 = *(const uint4*)(g2 + k0 + 8);
        uint4 e0 = *(const uint4*)(g3 + k0); uint4 e1 = *(const uint4*)(g3 + k0 + 8);
        uint4 f0 = *(const uint4*)(g4 + k0); uint4 f1 = *(const uint4*)(g4 + k0 + 8);
        uint4 h0 = *(const uint4*)(g5 + k0); uint4 h1 = *(const uint4*)(g5 + k0 + 8);
        *(uint4*)&lds[0*TSZ + d0] = a0; *(uint4*)&lds[0*TSZ + d1] = a1;
        *(uint4*)&lds[1*TSZ + d0] = b0; *(uint4*)&lds[1*TSZ + d1] = b1;
        *(uint4*)&lds[2*TSZ + d0] = c0; *(uint4*)&lds[2*TSZ + d1] = c1;
        *(uint4*)&lds[3*TSZ + d0] = e0; *(uint4*)&lds[3*TSZ + d1] = e1;
        *(uint4*)&lds[4*TSZ + d0] = f0; *(uint4*)&lds[4*TSZ + d1] = f1;
        *(uint4*)&lds[5*TSZ + d0] = h0; *(uint4*)&lds[5*TSZ + d1] = h1;
        __syncthreads();

        short8 a_h[4], a_l[4], a_q[4], b_h[4], b_l[4], b_q[4];
        #pragma unroll
        for (int m = 0; m < 4; ++m) {
            int off = (wr*64 + m*16 + fr) * TW + swz8;
            a_h[m] = *(const short8*)&lds[0*TSZ + off];
            a_l[m] = *(const short8*)&lds[1*TSZ + off];
            a_q[m] = *(const short8*)&lds[2*TSZ + off];
        }
        #pragma unroll
        for (int n = 0; n < 4; ++n) {
            int off = (wc*64 + n*16 + fr) * TW + swz8;
            b_h[n] = *(const short8*)&lds[3*TSZ + off];
            b_l[n] = *(const short8*)&lds[4*TSZ + off];
            b_q[n] = *(const short8*)&lds[5*TSZ + off];
        }
        #pragma unroll
        for (int m = 0; m < 4; ++m)
            #pragma unroll
            for (int n = 0; n < 4; ++n) {
                acc[m][n] = __builtin_amdgcn_mfma_f32_16x16x32_bf16(a_h[m], b_h[n], acc[m][n], 0, 0, 0);
                acc[m][n] = __builtin_amdgcn_mfma_f32_16x16x32_bf16(a_h[m], b_l[n], acc[m][n], 0, 0, 0);
                acc[m][n] = __builtin_amdgcn_mfma_f32_16x16x32_bf16(a_l[m], b_h[n], acc[m][n], 0, 0, 0);
                acc[m][n] = __builtin_amdgcn_mfma_f32_16x16x32_bf16(a_l[m], b_l[n], acc[m][n], 0, 0, 0);
                acc[m][n] = __builtin_amdgcn_mfma_f32_16x16x32_bf16(a_h[m], b_q[n], acc[m][n], 0, 0, 0);
                acc[m][n] = __builtin_amdgcn_mfma_f32_16x16x32_bf16(a_q[m], b_h[n], acc[m][n], 0, 0, 0);
            }
        __syncthreads();
    }

    // normal write: S[bi+row][bj+col] = x2[col] - 2 acc (diag -> inf)
    #pragma unroll
    for (int m = 0; m < 4; ++m)
        #pragma unroll
        for (int n = 0; n < 4; ++n) {
            int col = bj + wc*64 + n*16 + fr;
            float xc = x2b[col];
            #pragma unroll
            for (int r = 0; r < 4; ++r) {
                int row = bi + wr*64 + m*16 + kg*4 + r;
                float val = xc - 2.0f * acc[m][n][r];
                if (row == col) val = __builtin_inff();
                Sb[(size_t)row * NPTS + col] = val;
            }
        }

    // mirror write: S[bj+col][bi+row] = x2[row] - 2 acc, via LDS transpose
    if (bi != bj) {
        float* T = (float*)lds;                 // 64 x 128, stride 132 floats
        #pragma unroll
        for (int p = 0; p < 2; ++p) {
            __syncthreads();
            if (wc == p) {
                #pragma unroll
                for (int m = 0; m < 4; ++m) {
                    int row0 = wr*64 + m*16 + kg*4;
                    float x0 = x2b[bi + row0 + 0];
                    float x1 = x2b[bi + row0 + 1];
                    float x2v = x2b[bi + row0 + 2];
                    float x3 = x2b[bi + row0 + 3];
                    #pragma unroll
                    for (int n = 0; n < 4; ++n) {
                        int colp = n*16 + fr;   // 0..63 within pass
                        float4 v;
                        v.x = x0 - 2.0f * acc[m][n][0];
                        v.y = x1 - 2.0f * acc[m][n][1];
                        v.z = x2v - 2.0f * acc[m][n][2];
                        v.w = x3 - 2.0f * acc[m][n][3];
                        *(float4*)&T[colp * 132 + row0] = v;
                    }
                }
            }
            __syncthreads();
            #pragma unroll
            for (int i = 0; i < 8; ++i) {
                int f = threadIdx.x + i * 256;  // 0..2047
                int cr = f >> 5, c4 = (f & 31) * 4;
                float4 v = *(const float4*)&T[cr * 132 + c4];
                *(float4*)(Sb + (size_t)(bj + p*64 + cr) * NPTS + bi + c4) = v;
            }
        }
    }
}

// ---------------------------------------------------------------------------
// Kernel 2: static-grid MFMA kernel with BALANCED XCD-CHUNKED item mapping.
// blockIdx round-robins across the 8 XCDs; we give each XCD a contiguous
// run of 34 gram items + 48 qkv items (equal weight 34*2+48 = 116/XCD and
// panel-sharing neighbors stay in the same per-XCD L2).
// ---------------------------------------------------------------------------
__global__ __launch_bounds__(256) void fused_mfma_kernel(const ushort* __restrict__ xh,
                                                         const ushort* __restrict__ xl,
                                                         const ushort* __restrict__ xq,
                                                         const float* __restrict__ x2,
                                                         float* __restrict__ S,
                                                         const ushort* __restrict__ wqhiT,
                                                         const ushort* __restrict__ wqloT,
                                                         float* __restrict__ q,
                                                         ushort* __restrict__ kv16) {
    __shared__ ushort lds[6*TSZ];    // 48 KB -> 3 blocks/CU
    int bid = blockIdx.x;
    int xcd = bid & 7;
    int j   = bid >> 3;              // 0..81 within XCD
    int item = (j < 34) ? (xcd * 34 + j)
                        : (GRAM_ITEMS + xcd * 48 + (j - 34));
    if (item < GRAM_ITEMS) {
        int b = item / 136, t = item % 136;
        int by = 0;
        while (t >= 16 - by) { t -= 16 - by; ++by; }
        int bx = by + t;                 // by <= bx (upper triangle)
        size_t xoff = (size_t)b * NPTS * CDIM;
        gram_body(xh + xoff, xl + xoff, xq + xoff,
                  x2 + (size_t)b * NPTS, S + (size_t)b * NPTS * NPTS,
                  by * 128, bx * 128, lds);
    } else {
        int t = item - GRAM_ITEMS;       // 0..383
        int bx = t % 12, by = t / 12;
        gemm_split_body(xh, xl, wqhiT, wqloT, nullptr, q,
                        TRIPLE, CDIM, by * 128, bx * 128, lds, kv16);
    }
}

// ---------------------------------------------------------------------------
// Kernel 3: out projection (staged split GEMM + bias).
// ---------------------------------------------------------------------------
__global__ __launch_bounds__(256) void outproj_kernel(const ushort* __restrict__ Ahi,
                                                      const ushort* __restrict__ Alo,
                                                      const ushort* __restrict__ BhiT,
                                                      const ushort* __restrict__ BloT,
                                                      const float* __restrict__ bias,
                                                      float* __restrict__ C) {
    __shared__ ushort lds[4*TSZ];    // 32 KB
    gemm_split_body(Ahi, Alo, BhiT, BloT, bias, C,
                    CDIM, INNER, blockIdx.y * 128, blockIdx.x * 128, lds, nullptr);
}

// ---------------------------------------------------------------------------
// Kernel 4 (fused): top-KNN selection + sparse attention, one block per (b,n).
// ---------------------------------------------------------------------------
__device__ __forceinline__ unsigned block_excl_scan_256(unsigned c,
                                                        unsigned* wsum,
                                                        unsigned* total_out) {
    unsigned v = c;
    #pragma unroll
    for (int o = 1; o < 64; o <<= 1) {
        unsigned t = __shfl_up(v, o);
        if ((threadIdx.x & 63) >= o) v += t;
    }
    if ((threadIdx.x & 63) == 63) wsum[threadIdx.x >> 6] = v;
    __syncthreads();
    unsigned woff = 0;
    int mywave = threadIdx.x >> 6;
    #pragma unroll
    for (int w = 0; w < 4; ++w) {
        unsigned s = wsum[w];
        if (w < mywave) woff += s;
    }
    if (total_out) *total_out = wsum[0] + wsum[1] + wsum[2] + wsum[3];
    __syncthreads();
    return v + woff - c;
}

__global__ __launch_bounds__(256) void knn_attn_kernel(const float* __restrict__ S,
                                                       const float* __restrict__ q,
                                                       const ushort* __restrict__ kv16,
                                                       ushort* __restrict__ ahi,
                                                       ushort* __restrict__ alo) {
    int bid = blockIdx.x;
    int b = (bid & 7) >> 2;
    int n = ((bid >> 3) << 2) | (bid & 3);
    size_t rowoff = (size_t)b * NPTS + n;
    const float* row = S + rowoff * NPTS;

    __shared__ unsigned keys[NPTS];
    __shared__ unsigned hist[256];
    __shared__ unsigned wsum[4];
    __shared__ unsigned s_red[8];
    __shared__ unsigned sh_lo, sh_hi, sh_rank, sh_cnt, sh_break;
    __shared__ unsigned ckey[64];
    __shared__ int     cidx[64];
    __shared__ unsigned s_ccount;
    __shared__ int   nb[KNN];
    __shared__ float dots[NHEAD][KNN];
    __shared__ float p[NHEAD][KNN];

    int tid = threadIdx.x;

    // ---- selection phase ----
    unsigned mn = 0xffffffffu, mx = 0u;
    {
        int i0 = tid * 8;
        float4 f0 = *(const float4*)(row + i0);
        float4 f1 = *(const float4*)(row + i0 + 4);
        float fv[8] = { f0.x, f0.y, f0.z, f0.w, f1.x, f1.y, f1.z, f1.w };
        #pragma unroll
        for (int t = 0; t < 8; ++t) {
            int i = i0 + t;
            unsigned u;
            if (i == n) {
                u = 0xffffffffu;
            } else {
                unsigned v = __float_as_uint(fv[t]);
                u = (v & 0x80000000u) ? ~v : (v | 0x80000000u);
                mn = min(mn, u); mx = max(mx, u);
            }
            keys[i] = u;
        }
    }
    #pragma unroll
    for (int o = 32; o; o >>= 1) {
        mn = min(mn, (unsigned)__shfl_xor((int)mn, o));
        mx = max(mx, (unsigned)__shfl_xor((int)mx, o));
    }
    if ((tid & 63) == 0) { s_red[tid >> 6] = mn; s_red[4 + (tid >> 6)] = mx; }
    __syncthreads();
    if (tid == 0) {
        unsigned a = min(min(s_red[0], s_red[1]), min(s_red[2], s_red[3]));
        unsigned z = max(max(s_red[4], s_red[5]), max(s_red[6], s_red[7]));
        sh_lo = a; sh_hi = z; sh_rank = KNN; sh_break = 0; s_ccount = 0;
    }
    __syncthreads();

    for (int it = 0; it < 5; ++it) {
        unsigned lo = sh_lo, hi = sh_hi;
        unsigned range1 = hi - lo;
        int shift = 0;
        if (range1 > 255u) shift = 24 - __clz(range1);
        hist[tid] = 0;
        __syncthreads();
        for (int i = tid; i < NPTS; i += 256) {
            unsigned u = keys[i];
            if (u >= lo && u <= hi)
                atomicAdd(&hist[(u - lo) >> shift], 1u);
        }
        __syncthreads();
        unsigned c = hist[tid];
        unsigned rank = sh_rank;
        unsigned excl = block_excl_scan_256(c, wsum, nullptr);
        if (excl < rank && excl + c >= rank) {
            sh_rank = rank - excl;
            unsigned nlo = lo + ((unsigned)tid << shift);
            unsigned span = (shift == 0) ? 0u : (((1u << shift)) - 1u);
            unsigned nhi = nlo + span;
            if (nhi > hi || nhi < nlo) nhi = hi;
            sh_lo = nlo; sh_hi = nhi;
            sh_cnt = c;
            sh_break = (shift == 0 || c <= 64u) ? 1u : 0u;
        }
        __syncthreads();
        if (sh_break) break;
    }

    unsigned lo = sh_lo, hi = sh_hi, rank = sh_rank, cnt = sh_cnt;

    unsigned lt = 0;
    for (int i = tid; i < NPTS; i += 256) lt += (keys[i] < lo) ? 1u : 0u;
    unsigned pos = block_excl_scan_256(lt, wsum, nullptr);
    for (int i = tid; i < NPTS; i += 256) {
        unsigned u = keys[i];
        if (u < lo) nb[pos++] = i;
        else if (u >= lo && u <= hi && cnt <= 64u) {
            unsigned pp = atomicAdd(&s_ccount, 1u);
            ckey[pp] = u; cidx[pp] = i;
        }
    }
    __syncthreads();

    unsigned base = KNN - rank;
    if (cnt <= 64u) {
        if (tid < (int)cnt) {
            unsigned myk = ckey[tid]; int myi = cidx[tid];
            unsigned r = 0;
            for (unsigned s = 0; s < cnt; ++s) {
                unsigned sk = ckey[s]; int si = cidx[s];
                r += (sk < myk || (sk == myk && si < myi)) ? 1u : 0u;
            }
            if (r < rank) nb[base + r] = myi;
        }
    } else {
        if (tid == 0) {
            unsigned need = rank, pp = base;
            for (int i = 0; i < NPTS && need; ++i) {
                if (keys[i] >= lo && keys[i] <= hi) { nb[pp++] = i; --need; }
            }
        }
    }
    __syncthreads();

    // ---- attention phase (fp16 K/V gather, fp32 math) ----
    const float* qrow = q + rowoff * INNER;
    const ushort* kvb = kv16 + (size_t)b * NPTS * 1024;

    // phase 1: dots
    {
        int j = tid >> 3;              // neighbor 0..31
        int l = tid & 7;               // 8-elem segment 0..7
        const ushort* krow = kvb + (size_t)nb[j] * 1024 + l * 8;   // k at 0..511
        short8 kr[NHEAD];
        #pragma unroll
        for (int h = 0; h < NHEAD; ++h)
            kr[h] = *(const short8*)(krow + h * DHEAD);
        const float* qp = qrow + l * 8;
        #pragma unroll
        for (int h = 0; h < NHEAD; ++h) {
            float4 q0 = *(const float4*)(qp + h * DHEAD);
            float4 q1 = *(const float4*)(qp + h * DHEAD + 4);
            float d = h2f((ushort)kr[h][0]) * q0.x + h2f((ushort)kr[h][1]) * q0.y
                    + h2f((ushort)kr[h][2]) * q0.z + h2f((ushort)kr[h][3]) * q0.w
                    + h2f((ushort)kr[h][4]) * q1.x + h2f((ushort)kr[h][5]) * q1.y
                    + h2f((ushort)kr[h][6]) * q1.z + h2f((ushort)kr[h][7]) * q1.w;
            d += __shfl_xor(d, 1);
            d += __shfl_xor(d, 2);
            d += __shfl_xor(d, 4);
            if (l == 0) dots[h][j] = d * SCALE;
        }
    }
    __syncthreads();

    // phase 1b: softmax per head
    {
        int h = tid >> 5, jj = tid & 31;
        float dv = dots[h][jj];
        float mxv = dv;
        for (int o = 16; o; o >>= 1) mxv = fmaxf(mxv, __shfl_xor(mxv, o));
        float e = expf(dv - mxv);
        float s = e;
        for (int o = 16; o; o >>= 1) s += __shfl_xor(s, o);
        p[h][jj] = e / s;
    }
    __syncthreads();

    // phase 2: weighted V sum (fp16 V), 8 loads in flight per group
    {
        int hd = tid >> 5;
        int jd = tid & 31;
        const ushort* vb = kvb + INNER + hd * DHEAD + jd * 2;      // v at 512..1023
        float o0 = 0.f, o1 = 0.f;
        #pragma unroll
        for (int g = 0; g < 4; ++g) {
            unsigned vv[8]; float pw[8];
            #pragma unroll
            for (int t = 0; t < 8; ++t) {
                int jj = g * 8 + t;
                vv[t] = *(const unsigned*)(vb + (size_t)nb[jj] * 1024);
                pw[t] = p[hd][jj];
            }
            #pragma unroll
            for (int t = 0; t < 8; ++t) {
                o0 += pw[t] * h2f((ushort)(vv[t] & 0xffffu));
                o1 += pw[t] * h2f((ushort)(vv[t] >> 16));
            }
        }
        size_t baseo = rowoff * INNER + hd * DHEAD + jd * 2;
        unsigned q0 = bfsplit(o0);
        unsigned q1 = bfsplit(o1);
        *(unsigned*)(ahi + baseo) = (q0 & 0xffffu) | (q1 << 16);
        *(unsigned*)(alo + baseo) = (q0 >> 16) | (q1 & 0xffff0000u);
    }
}

// ---------------------------------------------------------------------------
extern "C" void kernel_launch(void* const* d_in, const int* in_sizes, int n_in,
                              void* d_out, int out_size, void* d_ws, size_t ws_size,
                              hipStream_t stream) {
    const float* x    = (const float*)d_in[0];   // [2,2048,256]
    const float* Wqkv = (const float*)d_in[1];   // [256,1536]
    const float* Wout = (const float*)d_in[2];   // [512,256]
    const float* bout = (const float*)d_in[3];   // [256]
    float* out = (float*)d_out;                  // [2,2048,256]

    // workspace layout
    float* S     = (float*)d_ws;                           // B*N*N f32
    float* x2    = S + (size_t)BATCH * NPTS * NPTS;        // B*N f32
    float* q     = x2 + (size_t)BATCH * NPTS;              // B*N*512 f32
    ushort* kv16 = (ushort*)(q + (size_t)BATCH * NPTS * INNER); // B*N*1024 fp16
    ushort* xhi  = kv16 + (size_t)BATCH * NPTS * 1024;
    ushort* xlo   = xhi   + (size_t)BATCH * NPTS * CDIM;
    ushort* xqd   = xlo   + (size_t)BATCH * NPTS * CDIM;
    ushort* ahi   = xqd   + (size_t)BATCH * NPTS * CDIM;
    ushort* alo   = ahi   + (size_t)BATCH * NPTS * INNER;
    ushort* wqhiT = alo   + (size_t)BATCH * NPTS * INNER;  // [1536][256]
    ushort* wqloT = wqhiT + (size_t)TRIPLE * CDIM;
    ushort* wohiT = wqloT + (size_t)TRIPLE * CDIM;         // [256][512]
    ushort* woloT = wohiT + (size_t)CDIM * INNER;

    // 1. merged prep: rowsq + x split + weight transposes
    prep_kernel<<<PREP_BLOCKS + WT_BLOCKS, 256, 0, stream>>>(
        x, x2, xhi, xlo, xqd, Wqkv, Wout, wqhiT, wqloT, wohiT, woloT);

    // 2. static gram (upper-tri + mirror) + qkv GEMM, balanced XCD-chunked
    fused_mfma_kernel<<<TOTAL_ITEMS, 256, 0, stream>>>(xhi, xlo, xqd, x2, S,
                                                       wqhiT, wqloT, q, kv16);

    // 3. fused top-32 selection + sparse attention (XCD batch pinning)
    knn_attn_kernel<<<BATCH * NPTS, 256, 0, stream>>>(S, q, kv16, ahi, alo);

    // 4. output projection: [4096,512] @ [512,256] + bias
    {
        dim3 grid(CDIM / 128, (BATCH * NPTS) / 128);
        outproj_kernel<<<grid, 256, 0, stream>>>(ahi, alo, wohiT, woloT, bout, out);
    }
}